// Round 9
// baseline (312.843 us; speedup 1.0000x reference)
//
#include <hip/hip_runtime.h>
#include <hip/hip_bf16.h>

typedef unsigned short u16;
typedef __attribute__((ext_vector_type(8))) short bfrag8;
typedef __attribute__((ext_vector_type(8))) unsigned short u16x8;
typedef __attribute__((ext_vector_type(4))) unsigned short u16x4;
typedef __attribute__((ext_vector_type(4))) float f32x4;

__device__ __forceinline__ float bf2f(u16 u) {
    union { unsigned int i; float f; } v; v.i = ((unsigned int)u) << 16; return v.f;
}
__device__ __forceinline__ u16 f2bf(float f) {
    union { __hip_bfloat16 h; u16 u; } cv;
    cv.h = __float2bfloat16(f);
    return cv.u;
}
__device__ __forceinline__ float fast_tanh(float x) {
    float e = __expf(2.f * x);
    return (e - 1.f) / (e + 1.f);
}

#define TILE_M 128
#define TILE_N 128
#define TILE_K 32

#define GLOAD_LDS16(g, l) \
    __builtin_amdgcn_global_load_lds( \
        (const __attribute__((address_space(1))) void*)(g), \
        (__attribute__((address_space(3))) void*)(l), 16, 0, 0)

// C(M,N) = A(M,K)bf16 @ Wt(N,K)^T (+bias at kc==0). m97 structure: single-
// buffered linear LDS, global_load_lds width=16 staging. XCD swizzle (m204).
// C_MODE: 0 = bf16 store, 1 = f32 store at slice kc*M*ldc (split-K partials;
// summed later — replaces R8's atomicAdd + hipMemsetAsync, whose runtime fill
// kernel cost 66 us/replay at 79 GB/s).
template<int HAS_BIAS, int C_MODE, int NGUARD>
__global__ __launch_bounds__(256)
void gemm_k(const u16* __restrict__ A, const u16* __restrict__ Bt,
            const float* __restrict__ bias, void* __restrict__ Cp,
            int M, int N, int K, int lda, int ldc, int nt, int kchunk)
{
    __shared__ u16 As[TILE_M][TILE_K];
    __shared__ u16 Bs[TILE_N][TILE_K];

    const int nwg = gridDim.x;
    const int q = nwg >> 3, r = nwg & 7;
    const int xcd = blockIdx.x & 7, pos = blockIdx.x >> 3;
    const int wg = (xcd < r ? xcd * (q + 1) : r * (q + 1) + (xcd - r) * q) + pos;
    const int m0 = (wg / nt) * TILE_M;
    const int n0 = (wg % nt) * TILE_N;

    const int kc   = blockIdx.y;
    const int kbeg = kc * kchunk;
    const int kend = (kbeg + kchunk < K) ? kbeg + kchunk : K;

    const int t    = threadIdx.x;
    const int lane = t & 63;
    const int w    = t >> 6;
    const int wm   = (w >> 1) * 64;
    const int wn   = (w & 1) * 64;
    const int lr   = lane & 15;
    const int kg   = (lane >> 4) * 8;

    const int lrow = lane >> 2;          // 0..15
    const int lcol = (lane & 3) * 8;     // 0,8,16,24
    const u16* gA0 = A  + (size_t)(m0 + 32 * w + lrow) * lda + lcol;
    const u16* gA1 = gA0 + (size_t)16 * lda;
    const u16* gB0 = Bt + (size_t)(n0 + 32 * w + lrow) * K + lcol;
    const u16* gB1 = gB0 + (size_t)16 * K;
    char* lA0 = (char*)&As[0][0] + w * 2048;
    char* lA1 = lA0 + 1024;
    char* lB0 = (char*)&Bs[0][0] + w * 2048;
    char* lB1 = lB0 + 1024;

    f32x4 acc[4][4];
#pragma unroll
    for (int i = 0; i < 4; ++i)
#pragma unroll
        for (int j = 0; j < 4; ++j) acc[i][j] = (f32x4){0.f, 0.f, 0.f, 0.f};

    for (int k0 = kbeg; k0 < kend; k0 += TILE_K) {
        GLOAD_LDS16(gA0 + k0, lA0);
        GLOAD_LDS16(gA1 + k0, lA1);
        GLOAD_LDS16(gB0 + k0, lB0);
        GLOAD_LDS16(gB1 + k0, lB1);
        asm volatile("s_waitcnt vmcnt(0)" ::: "memory");
        __syncthreads();

        bfrag8 af[4], bfr[4];
#pragma unroll
        for (int mi = 0; mi < 4; ++mi) af[mi]  = *(const bfrag8*)&As[wm + mi * 16 + lr][kg];
#pragma unroll
        for (int ni = 0; ni < 4; ++ni) bfr[ni] = *(const bfrag8*)&Bs[wn + ni * 16 + lr][kg];
#pragma unroll
        for (int mi = 0; mi < 4; ++mi)
#pragma unroll
            for (int ni = 0; ni < 4; ++ni)
                acc[mi][ni] = __builtin_amdgcn_mfma_f32_16x16x32_bf16(af[mi], bfr[ni], acc[mi][ni], 0, 0, 0);

        __syncthreads();
    }

    float* Cf = (float*)Cp + (size_t)kc * M * ldc;   // split-K partial slice
#pragma unroll
    for (int mi = 0; mi < 4; ++mi) {
#pragma unroll
        for (int ni = 0; ni < 4; ++ni) {
            int col = n0 + wn + ni * 16 + lr;
            if (!NGUARD || col < N) {
                int row = m0 + wm + mi * 16 + (lane >> 4) * 4;
                float bv = 0.f;
                if (HAS_BIAS && kc == 0) bv = bias[col];
#pragma unroll
                for (int rr = 0; rr < 4; ++rr) {
                    float v = acc[mi][ni][rr] + bv;
                    if (C_MODE == 0) ((u16*)Cp)[(size_t)(row + rr) * ldc + col] = f2bf(v);
                    else             Cf[(size_t)(row + rr) * ldc + col] = v;
                }
            }
        }
    }
}

// f32 -> bf16 streaming cast (HBM-bound), 8 elems/thread.
__global__ __launch_bounds__(256)
void precast_k(const float* __restrict__ in, u16* __restrict__ out, int n8)
{
    int i = blockIdx.x * 256 + threadIdx.x;
    if (i >= n8) return;
    const float4* p = (const float4*)(in + (size_t)i * 8);
    float4 a = p[0], b = p[1];
    u16x8 v;
    v[0] = f2bf(a.x); v[1] = f2bf(a.y); v[2] = f2bf(a.z); v[3] = f2bf(a.w);
    v[4] = f2bf(b.x); v[5] = f2bf(b.y); v[6] = f2bf(b.z); v[7] = f2bf(b.w);
    *(u16x8*)(out + (size_t)i * 8) = v;
}

// scores[row][8] = [s_src h0..3, s_dst h0..3]; one wave per row of h (bf16).
__global__ __launch_bounds__(256)
void score_k(const u16* __restrict__ hs, int ld,
             const float* __restrict__ a_src, const float* __restrict__ a_dst,
             float* __restrict__ scores, int Mrows)
{
    const int wid  = blockIdx.x * 4 + (threadIdx.x >> 6);
    const int lane = threadIdx.x & 63;
    if (wid >= Mrows) return;
    const u16* hp = hs + (size_t)wid * ld + lane * 4;
    u16x4 xv = *(const u16x4*)hp;
    float s1 = 0.f, s2 = 0.f;
#pragma unroll
    for (int k = 0; k < 4; ++k) {
        float x = bf2f(xv[k]);
        s1 = fmaf(x, a_src[lane * 4 + k], s1);
        s2 = fmaf(x, a_dst[lane * 4 + k], s2);
    }
#pragma unroll
    for (int off = 1; off < 16; off <<= 1) {
        s1 += __shfl_xor(s1, off);
        s2 += __shfl_xor(s2, off);
    }
    if ((lane & 15) == 0) {
        scores[(size_t)wid * 8 + (lane >> 4)] = s1;
        scores[(size_t)wid * 8 + 4 + (lane >> 4)] = s2;
    }
}

// One thread per (b,h): full 7x7 leaky-relu + mask + top-3 + softmax.
template<int WRITE_ATTN>
__global__ __launch_bounds__(256)
void alpha_k(const float* __restrict__ scores, const float* __restrict__ em2,
             float* __restrict__ alpha, float* __restrict__ attn_out)
{
    const int t = blockIdx.x * 256 + threadIdx.x;
    const int b = t >> 2;
    const int h = t & 3;

    float ssrc[7], sdst[7];
#pragma unroll
    for (int n = 0; n < 7; ++n) {
        ssrc[n] = scores[(size_t)(b * 7 + n) * 8 + h];
        sdst[n] = scores[(size_t)(b * 7 + n) * 8 + 4 + h];
    }

    float al[49];
#pragma unroll
    for (int i = 0; i < 7; ++i) {
        float e[7];
#pragma unroll
        for (int j = 0; j < 7; ++j) {
            float v = ssrc[i] + sdst[j];
            v = fmaxf(v, 0.2f * v);
            e[j] = fmaf(v, em2[(i * 7 + j) * 2], em2[(i * 7 + j) * 2 + 1]);
        }
        float a1 = -3e38f, b1 = -3e38f, c1 = -3e38f;
#pragma unroll
        for (int j = 0; j < 7; ++j) {
            float v = e[j];
            float t2 = fminf(a1, v); a1 = fmaxf(a1, v);
            float t3 = fminf(b1, t2); b1 = fmaxf(b1, t2);
            c1 = fmaxf(c1, t3);
        }
        float psum = 0.f;
        float p[7];
#pragma unroll
        for (int j = 0; j < 7; ++j) {
            float qv = (e[j] >= c1) ? __expf(e[j] - a1) : 0.f;
            p[j] = qv; psum += qv;
        }
        float inv = 1.f / psum;
#pragma unroll
        for (int j = 0; j < 7; ++j) al[i * 7 + j] = p[j] * inv;
    }

    float* ap = alpha + (size_t)t * 49;
#pragma unroll
    for (int j = 0; j < 49; ++j) ap[j] = al[j];

    if (WRITE_ATTN) {
#pragma unroll
        for (int j = 0; j < 49; ++j) {
            float m = al[j];
            m += __shfl_xor(m, 1);
            m += __shfl_xor(m, 2);
            if (h == 0) attn_out[(size_t)b * 49 + j] = 0.25f * m;
        }
    }
}

// PV + residual + LN + relu. One wave per batch element; lane owns 4 cols.
__global__ __launch_bounds__(256)
void gat_apply_k(const u16* __restrict__ hh, int ld_hh,
                 const u16* __restrict__ resid, int ld_res, int res_off,
                 const float* __restrict__ alpha,
                 const float* __restrict__ ln_w, const float* __restrict__ ln_b,
                 u16* __restrict__ outp, int out_bs)
{
    const int t = threadIdx.x;
    const int b = blockIdx.x * 4 + (t >> 6);
    const int l = t & 63;
    const int c = l * 4;
    const int h = l >> 4;
    const size_t rowbase = (size_t)b * 7;

    float hv[7][4];
#pragma unroll
    for (int n = 0; n < 7; ++n) {
        u16x4 qv = *(const u16x4*)&hh[(rowbase + n) * ld_hh + c];
#pragma unroll
        for (int k = 0; k < 4; ++k) hv[n][k] = bf2f(qv[k]);
    }

    const float* ap = alpha + ((size_t)b * 4 + h) * 49;
    float4 lw = *(const float4*)&ln_w[c];
    float4 lb = *(const float4*)&ln_b[c];

#pragma unroll
    for (int i = 0; i < 7; ++i) {
        float a0 = ap[i * 7 + 0], a1 = ap[i * 7 + 1], a2 = ap[i * 7 + 2],
              a3 = ap[i * 7 + 3], a4 = ap[i * 7 + 4], a5 = ap[i * 7 + 5],
              a6 = ap[i * 7 + 6];
        u16x4 rr = *(const u16x4*)&resid[(rowbase + i) * ld_res + res_off + c];
        float x[4];
#pragma unroll
        for (int k = 0; k < 4; ++k) {
            float pv = a0 * hv[0][k];
            pv = fmaf(a1, hv[1][k], pv);
            pv = fmaf(a2, hv[2][k], pv);
            pv = fmaf(a3, hv[3][k], pv);
            pv = fmaf(a4, hv[4][k], pv);
            pv = fmaf(a5, hv[5][k], pv);
            pv = fmaf(a6, hv[6][k], pv);
            x[k] = pv + bf2f(rr[k]);
        }
        float s1 = (x[0] + x[1]) + (x[2] + x[3]);
        float s2 = fmaf(x[0], x[0], x[1] * x[1]) + fmaf(x[2], x[2], x[3] * x[3]);
#pragma unroll
        for (int off = 32; off > 0; off >>= 1) {
            s1 += __shfl_xor(s1, off);
            s2 += __shfl_xor(s2, off);
        }
        float mu  = s1 * (1.f / 256.f);
        float var = fmaxf(s2 * (1.f / 256.f) - mu * mu, 0.f);
        float inv = rsqrtf(var + 1e-5f);
        u16x4 o;
        o[0] = f2bf(fmaxf((x[0] - mu) * inv * lw.x + lb.x, 0.f));
        o[1] = f2bf(fmaxf((x[1] - mu) * inv * lw.y + lb.y, 0.f));
        o[2] = f2bf(fmaxf((x[2] - mu) * inv * lw.z + lb.z, 0.f));
        o[3] = f2bf(fmaxf((x[3] - mu) * inv * lw.w + lb.w, 0.f));
        *(u16x4*)&outp[(size_t)b * out_bs + i * 256 + c] = o;
    }
}

// weight transpose/cast + bias fuse + edge_mask. Wt3 padded to 128 rows.
__global__ __launch_bounds__(256)
void prep_k(const float* __restrict__ W1, const float* __restrict__ skip_w, const float* __restrict__ W2,
            const float* __restrict__ base_w1, const float* __restrict__ reg_w1, const float* __restrict__ res_w1,
            const float* __restrict__ skip_b, const float* __restrict__ base_b1, const float* __restrict__ reg_b1,
            const float* __restrict__ res_b1, const float* __restrict__ edge_logits,
            u16* __restrict__ Wt1, u16* __restrict__ Wt2, u16* __restrict__ Wt3,
            float* __restrict__ bias1, float* __restrict__ bias3,
            float* __restrict__ em2, float* __restrict__ em_out)
{
    int idx = blockIdx.x * 256 + threadIdx.x;
    if (idx < 512 * 256) {            // Wt1[n][k] = [W1|skip_w][k][n]
        int n = idx >> 8, k = idx & 255;
        float v = (n < 256) ? W1[k * 256 + n] : skip_w[k * 256 + (n - 256)];
        Wt1[n * 256 + k] = f2bf(v); return;
    }
    idx -= 512 * 256;
    if (idx < 256 * 256) {
        int n = idx >> 8, k = idx & 255;
        Wt2[n * 256 + k] = f2bf(W2[k * 256 + n]); return;
    }
    idx -= 256 * 256;
    if (idx < 128 * 1920) {           // Wt3 rows 80..127 zero
        int n = idx / 1920, k = idx % 1920;
        float v = (n < 32) ? base_w1[k * 32 + n]
                : (n < 64) ? reg_w1[k * 32 + (n - 32)]
                : (n < 80) ? res_w1[k * 16 + (n - 64)] : 0.f;
        Wt3[n * 1920 + k] = f2bf(v); return;
    }
    idx -= 128 * 1920;
    if (idx < 512) { bias1[idx] = (idx < 256) ? 0.f : skip_b[idx - 256]; return; }
    idx -= 512;
    if (idx < 80) {
        bias3[idx] = (idx < 32) ? base_b1[idx] : (idx < 64) ? reg_b1[idx - 32] : res_b1[idx - 64];
        return;
    }
    idx -= 80;
    if (idx < 49) {
        int i = idx / 7, j = idx % 7;
        float s = 1.f / (1.f + __expf(-edge_logits[idx]));
        float m = (i == j) ? 1.f : s;
        em2[idx * 2] = m;
        em2[idx * 2 + 1] = (1.f - m) * (-1e9f);
        em_out[idx] = m;
    }
}

__global__ __launch_bounds__(256)
void ctx_k(const float* __restrict__ ctx, u16* __restrict__ comb)
{
    int idx = blockIdx.x * 256 + threadIdx.x;   // B*128
    int b = idx >> 7, cc = idx & 127;
    comb[(size_t)b * 1920 + 1792 + cc] = f2bf(ctx[idx]);
}

// Heads; ho0/ho1 are the two split-K partial slices of the head GEMM (sum here
// instead of atomics-onto-memset — the runtime fill kernel cost 66 us/replay).
__global__ __launch_bounds__(256)
void head_finish(const float* __restrict__ ho0, const float* __restrict__ ho1,
                 const float* __restrict__ bp, const float* __restrict__ rf,
                 const float* __restrict__ bw2, const float* __restrict__ bb2,
                 const float* __restrict__ rw2, const float* __restrict__ rb2,
                 const float* __restrict__ gw1, const float* __restrict__ gb1,
                 const float* __restrict__ gw2, const float* __restrict__ gb2,
                 const float* __restrict__ resw2, const float* __restrict__ resb2,
                 float* __restrict__ out_pred, float* __restrict__ out_w, float* __restrict__ out_gate, int B)
{
    int b = blockIdx.x * 256 + threadIdx.x;
    if (b >= B) return;
    const float* p0 = ho0 + (size_t)b * 80;
    const float* p1 = ho1 + (size_t)b * 80;
    float o[80];
#pragma unroll 16
    for (int k = 0; k < 80; ++k) o[k] = p0[k] + p1[k];

    float z0 = bb2[0], z1 = bb2[1];
#pragma unroll 8
    for (int k = 0; k < 32; ++k) { float v = fmaxf(o[k], 0.f); z0 += v * bw2[k * 2]; z1 += v * bw2[k * 2 + 1]; }
    float mz = fmaxf(z0, z1); float e0 = __expf(z0 - mz), e1 = __expf(z1 - mz); float inv = 1.f / (e0 + e1);
    float wb0 = e0 * inv, wb1 = e1 * inv;

    z0 = rb2[0]; z1 = rb2[1];
#pragma unroll 8
    for (int k = 0; k < 32; ++k) { float v = fmaxf(o[32 + k], 0.f); z0 += v * rw2[k * 2]; z1 += v * rw2[k * 2 + 1]; }
    mz = fmaxf(z0, z1); e0 = __expf(z0 - mz); e1 = __expf(z1 - mz); inv = 1.f / (e0 + e1);
    float wr0 = e0 * inv, wr1 = e1 * inv;

    float g = gb2[0];
#pragma unroll
    for (int j = 0; j < 8; ++j) {
        float a = gb1[j];
#pragma unroll
        for (int i = 0; i < 3; ++i) a += rf[(size_t)b * 3 + i] * gw1[i * 8 + j];
        g += fast_tanh(a) * gw2[j];
    }
    float gg = 1.f / (1.f + __expf(-g));
    float w0 = (1.f - gg) * wb0 + gg * wr0;
    float w1 = (1.f - gg) * wb1 + gg * wr1;
    float pred = w0 * bp[(size_t)b * 2] + w1 * bp[(size_t)b * 2 + 1];
    float r = resb2[0];
#pragma unroll 8
    for (int k = 0; k < 16; ++k) r += fast_tanh(o[64 + k]) * resw2[k];
    pred = fmaxf(pred + r * 0.05f, 0.05f);
    out_pred[b] = pred;
    out_w[(size_t)b * 2] = w0; out_w[(size_t)b * 2 + 1] = w1;
    out_gate[b] = gg;
}

extern "C" void kernel_launch(void* const* d_in, const int* in_sizes, int n_in,
                              void* d_out, int out_size, void* d_ws, size_t ws_size,
                              hipStream_t stream)
{
    const int B = in_sizes[1] / 128;     // context is (B,128)
    const int Mbig = B * 7;

    const float* node_feats   = (const float*)d_in[0];
    const float* context      = (const float*)d_in[1];
    const float* base_preds   = (const float*)d_in[2];
    const float* regime_feats = (const float*)d_in[3];
    const float* edge_logits  = (const float*)d_in[4];
    const float* W1      = (const float*)d_in[5];
    const float* a_src1  = (const float*)d_in[6];
    const float* a_dst1  = (const float*)d_in[7];
    const float* W2      = (const float*)d_in[8];
    const float* a_src2  = (const float*)d_in[9];
    const float* a_dst2  = (const float*)d_in[10];
    const float* ln1_w   = (const float*)d_in[11];
    const float* ln1_b   = (const float*)d_in[12];
    const float* ln2_w   = (const float*)d_in[13];
    const float* ln2_b   = (const float*)d_in[14];
    const float* skip_w  = (const float*)d_in[15];
    const float* skip_b  = (const float*)d_in[16];
    const float* base_w1 = (const float*)d_in[17];
    const float* base_b1 = (const float*)d_in[18];
    const float* base_w2 = (const float*)d_in[19];
    const float* base_b2 = (const float*)d_in[20];
    const float* reg_w1  = (const float*)d_in[21];
    const float* reg_b1  = (const float*)d_in[22];
    const float* reg_w2  = (const float*)d_in[23];
    const float* reg_b2  = (const float*)d_in[24];
    const float* gate_w1 = (const float*)d_in[25];
    const float* gate_b1 = (const float*)d_in[26];
    const float* gate_w2 = (const float*)d_in[27];
    const float* gate_b2 = (const float*)d_in[28];
    const float* res_w1  = (const float*)d_in[29];
    const float* res_b1  = (const float*)d_in[30];
    const float* res_w2  = (const float*)d_in[31];
    const float* res_b2  = (const float*)d_in[32];

    // workspace layout (bytes)
    char* ws = (char*)d_ws;
    size_t off = 0;
    u16* hs1 = (u16*)(ws + off);                       // [h1_pre|skip] Mbig x 512 bf16
    u16* hh2 = (u16*)(ws + off);                       // reuse after GAT1: Mbig x 256 bf16
    off += (size_t)Mbig * 512 * 2;
    u16* hbuf = (u16*)(ws + off);  off += (size_t)Mbig * 256 * 2;   // h: Mbig x 256 bf16
    u16* comb = (u16*)(ws + off);  off += (size_t)B * 1920 * 2;     // combined: B x 1920 bf16
    u16* nf_bf = comb;             // A1 bf16 aliases comb (dead until step 9)
    float* headout = (float*)(ws + off); off += (size_t)2 * B * 80 * 4; // 2 split-K slices
    u16* Wt1 = (u16*)(ws + off); off += 512 * 256 * 2;
    u16* Wt2 = (u16*)(ws + off); off += 256 * 256 * 2;
    u16* Wt3 = (u16*)(ws + off); off += (size_t)128 * 1920 * 2;     // padded to 128 rows
    float* bias1 = (float*)(ws + off); off += 512 * 4;
    float* bias3 = (float*)(ws + off); off += 128 * 4;
    float* em2   = (float*)(ws + off); off += 128 * 4;
    float* scoresb = (float*)(ws + off); off += (size_t)Mbig * 8 * 4;   // row scores f32
    float* alphab  = (float*)(ws + off); off += (size_t)B * 4 * 49 * 4; // alpha f32

    float* out_pred = (float*)d_out;
    float* out_w    = out_pred + B;
    float* out_gate = out_pred + 3 * (size_t)B;
    float* out_em   = out_pred + 4 * (size_t)B;
    float* out_attn = out_pred + 4 * (size_t)B + 49;

    const int B4blocks = (B * 4) / 256;

    // 0. node_feats f32 -> bf16 (HBM-bound streaming pass)
    {
        int n8 = Mbig * 256 / 8;
        precast_k<<<dim3((n8 + 255) / 256), dim3(256), 0, stream>>>(node_feats, nf_bf, n8);
    }

    // 1. weight prep + edge mask
    prep_k<<<dim3(1731), dim3(256), 0, stream>>>(W1, skip_w, W2, base_w1, reg_w1, res_w1,
        skip_b, base_b1, reg_b1, res_b1, edge_logits, Wt1, Wt2, Wt3, bias1, bias3, em2, out_em);

    // 2. GEMM1: nf_bf @ [W1|skip_w] -> hs1 (bf16), bias=[0|skip_b]
    gemm_k<1, 0, 0><<<dim3((Mbig / 128) * 4, 1), dim3(256), 0, stream>>>(
        nf_bf, Wt1, bias1, (void*)hs1, Mbig, 512, 256, 256, 512, 4, 256);

    // 3. scores from h1 (= hs1 cols 0..255)
    score_k<<<dim3(Mbig / 4), dim3(256), 0, stream>>>(hs1, 512, a_src1, a_dst1, scoresb, Mbig);

    // 4. alpha for GAT1
    alpha_k<0><<<dim3(B4blocks), dim3(256), 0, stream>>>(scoresb, em2, alphab, (float*)nullptr);

    // 5. GAT1 apply: PV + skip-resid + LN1 + relu -> hbuf
    gat_apply_k<<<dim3(B / 4), dim3(256), 0, stream>>>(
        hs1, 512, hs1, 512, 256, alphab, ln1_w, ln1_b, hbuf, 1792);

    // 6. GEMM2: h @ W2 -> hh2 (reuses hs1 region)
    gemm_k<0, 0, 0><<<dim3((Mbig / 128) * 2, 1), dim3(256), 0, stream>>>(
        hbuf, Wt2, (const float*)nullptr, (void*)hh2, Mbig, 256, 256, 256, 256, 2, 256);

    // 7. scores from h2
    score_k<<<dim3(Mbig / 4), dim3(256), 0, stream>>>(hh2, 256, a_src2, a_dst2, scoresb, Mbig);

    // 8. alpha for GAT2 (+ attn mean output)
    alpha_k<1><<<dim3(B4blocks), dim3(256), 0, stream>>>(scoresb, em2, alphab, out_attn);

    // 9. GAT2 apply: PV + h-resid + LN2 + relu -> comb[:, :1792]
    gat_apply_k<<<dim3(B / 4), dim3(256), 0, stream>>>(
        hh2, 256, hbuf, 256, 0, alphab, ln2_w, ln2_b, comb, 1920);

    // 10. context -> comb[:, 1792:]
    ctx_k<<<dim3(B * 128 / 256), dim3(256), 0, stream>>>(context, comb);

    // 11. GEMM3: comb @ padded-Wt3 + bias -> two partial slices (no memset/atomics)
    gemm_k<1, 1, 1><<<dim3(B / 128, 2), dim3(256), 0, stream>>>(
        comb, Wt3, bias3, (void*)headout, B, 80, 1920, 1920, 80, 1, 960);

    // 12. heads -> pred, weights, gate (sums the two partials)
    head_finish<<<dim3((B + 255) / 256), dim3(256), 0, stream>>>(
        headout, headout + (size_t)B * 80, base_preds, regime_feats, base_w2, base_b2, reg_w2, reg_b2,
        gate_w1, gate_b1, gate_w2, gate_b2, res_w2, res_b2, out_pred, out_w, out_gate, B);
}

// Round 10
// 301.177 us; speedup vs baseline: 1.0387x; 1.0387x over previous
//
#include <hip/hip_runtime.h>
#include <hip/hip_bf16.h>

typedef unsigned short u16;
typedef __attribute__((ext_vector_type(8))) short bfrag8;
typedef __attribute__((ext_vector_type(8))) unsigned short u16x8;
typedef __attribute__((ext_vector_type(4))) unsigned short u16x4;
typedef __attribute__((ext_vector_type(4))) float f32x4;

__device__ __forceinline__ float bf2f(u16 u) {
    union { unsigned int i; float f; } v; v.i = ((unsigned int)u) << 16; return v.f;
}
__device__ __forceinline__ u16 f2bf(float f) {
    union { __hip_bfloat16 h; u16 u; } cv;
    cv.h = __float2bfloat16(f);
    return cv.u;
}
__device__ __forceinline__ float fast_tanh(float x) {
    float e = __expf(2.f * x);
    return (e - 1.f) / (e + 1.f);
}

#define TILE_M 128
#define TILE_N 128
#define TILE_K 32

#define GLOAD_LDS16(g, l) \
    __builtin_amdgcn_global_load_lds( \
        (const __attribute__((address_space(1))) void*)(g), \
        (__attribute__((address_space(3))) void*)(l), 16, 0, 0)

// C(M,N) = A(M,K)bf16 @ Wt(N,K)^T (+bias at kc==0). m97 loop upgraded with a
// 2-deep global_load_lds double-buffer + COUNTED vmcnt (T3/T4-minimum): buf^1's
// 4 DMAs are issued BEFORE s_waitcnt vmcnt(4), so they stay in flight across
// the entire MFMA phase (R9 was vmcnt(0)-drained each step: MfmaUtil 17%,
// HBM 33%, latency-bound at ~2 blocks/CU). Per-wave vmcnt(4) + barrier =>
// all 4 waves' loads for the current buffer have landed. XCD swizzle (m204).
// C_MODE: 0 = bf16 store, 1 = f32 store at slice kc*M*ldc (split-K partials).
template<int HAS_BIAS, int C_MODE, int NGUARD>
__global__ __launch_bounds__(256)
void gemm_k(const u16* __restrict__ A, const u16* __restrict__ Bt,
            const float* __restrict__ bias, void* __restrict__ Cp,
            int M, int N, int K, int lda, int ldc, int nt, int kchunk)
{
    __shared__ u16 As[2][TILE_M][TILE_K];   // 2 x 8 KB
    __shared__ u16 Bs[2][TILE_N][TILE_K];

    const int nwg = gridDim.x;
    const int q = nwg >> 3, r = nwg & 7;
    const int xcd = blockIdx.x & 7, pos = blockIdx.x >> 3;
    const int wg = (xcd < r ? xcd * (q + 1) : r * (q + 1) + (xcd - r) * q) + pos;
    const int m0 = (wg / nt) * TILE_M;
    const int n0 = (wg % nt) * TILE_N;

    const int kc   = blockIdx.y;
    const int kbeg = kc * kchunk;
    const int kend = (kbeg + kchunk < K) ? kbeg + kchunk : K;

    const int t    = threadIdx.x;
    const int lane = t & 63;
    const int w    = t >> 6;
    const int wm   = (w >> 1) * 64;
    const int wn   = (w & 1) * 64;
    const int lr   = lane & 15;
    const int kg   = (lane >> 4) * 8;

    const int lrow = lane >> 2;          // 0..15
    const int lcol = (lane & 3) * 8;     // 0,8,16,24
    const u16* gA0 = A  + (size_t)(m0 + 32 * w + lrow) * lda + lcol;
    const u16* gA1 = gA0 + (size_t)16 * lda;
    const u16* gB0 = Bt + (size_t)(n0 + 32 * w + lrow) * K + lcol;
    const u16* gB1 = gB0 + (size_t)16 * K;
    char* lA = (char*)&As[0][0][0] + w * 2048;   // + buf*8192
    char* lB = (char*)&Bs[0][0][0] + w * 2048;

    f32x4 acc[4][4];
#pragma unroll
    for (int i = 0; i < 4; ++i)
#pragma unroll
        for (int j = 0; j < 4; ++j) acc[i][j] = (f32x4){0.f, 0.f, 0.f, 0.f};

#define ISSUE(bufo, k0v) { \
        GLOAD_LDS16(gA0 + (k0v), lA + (bufo)); \
        GLOAD_LDS16(gA1 + (k0v), lA + 1024 + (bufo)); \
        GLOAD_LDS16(gB0 + (k0v), lB + (bufo)); \
        GLOAD_LDS16(gB1 + (k0v), lB + 1024 + (bufo)); \
    }

    ISSUE(0, kbeg)
    int buf = 0;
    for (int k0 = kbeg; k0 < kend; k0 += TILE_K) {
        const bool more = (k0 + TILE_K) < kend;
        if (more) {
            ISSUE((buf ^ 1) * 8192, k0 + TILE_K);             // 4 new in flight
            asm volatile("s_waitcnt vmcnt(4)" ::: "memory");  // wait cur buf's 4
        } else {
            asm volatile("s_waitcnt vmcnt(0)" ::: "memory");
        }
        __syncthreads();

        bfrag8 af[4], bfr[4];
#pragma unroll
        for (int mi = 0; mi < 4; ++mi) af[mi]  = *(const bfrag8*)&As[buf][wm + mi * 16 + lr][kg];
#pragma unroll
        for (int ni = 0; ni < 4; ++ni) bfr[ni] = *(const bfrag8*)&Bs[buf][wn + ni * 16 + lr][kg];
#pragma unroll
        for (int mi = 0; mi < 4; ++mi)
#pragma unroll
            for (int ni = 0; ni < 4; ++ni)
                acc[mi][ni] = __builtin_amdgcn_mfma_f32_16x16x32_bf16(af[mi], bfr[ni], acc[mi][ni], 0, 0, 0);

        __syncthreads();   // all waves done reading buf before its next DMA
        buf ^= 1;
    }
#undef ISSUE

    float* Cf = (float*)Cp + (size_t)kc * M * ldc;   // split-K partial slice
#pragma unroll
    for (int mi = 0; mi < 4; ++mi) {
#pragma unroll
        for (int ni = 0; ni < 4; ++ni) {
            int col = n0 + wn + ni * 16 + lr;
            if (!NGUARD || col < N) {
                int row = m0 + wm + mi * 16 + (lane >> 4) * 4;
                float bv = 0.f;
                if (HAS_BIAS && kc == 0) bv = bias[col];
#pragma unroll
                for (int rr = 0; rr < 4; ++rr) {
                    float v = acc[mi][ni][rr] + bv;
                    if (C_MODE == 0) ((u16*)Cp)[(size_t)(row + rr) * ldc + col] = f2bf(v);
                    else             Cf[(size_t)(row + rr) * ldc + col] = v;
                }
            }
        }
    }
}

// f32 -> bf16 streaming cast (HBM-bound), 8 elems/thread.
__global__ __launch_bounds__(256)
void precast_k(const float* __restrict__ in, u16* __restrict__ out, int n8)
{
    int i = blockIdx.x * 256 + threadIdx.x;
    if (i >= n8) return;
    const float4* p = (const float4*)(in + (size_t)i * 8);
    float4 a = p[0], b = p[1];
    u16x8 v;
    v[0] = f2bf(a.x); v[1] = f2bf(a.y); v[2] = f2bf(a.z); v[3] = f2bf(a.w);
    v[4] = f2bf(b.x); v[5] = f2bf(b.y); v[6] = f2bf(b.z); v[7] = f2bf(b.w);
    *(u16x8*)(out + (size_t)i * 8) = v;
}

// scores[row][8] = [s_src h0..3, s_dst h0..3]; one wave per row of h (bf16).
__global__ __launch_bounds__(256)
void score_k(const u16* __restrict__ hs, int ld,
             const float* __restrict__ a_src, const float* __restrict__ a_dst,
             float* __restrict__ scores, int Mrows)
{
    const int wid  = blockIdx.x * 4 + (threadIdx.x >> 6);
    const int lane = threadIdx.x & 63;
    if (wid >= Mrows) return;
    const u16* hp = hs + (size_t)wid * ld + lane * 4;
    u16x4 xv = *(const u16x4*)hp;
    float s1 = 0.f, s2 = 0.f;
#pragma unroll
    for (int k = 0; k < 4; ++k) {
        float x = bf2f(xv[k]);
        s1 = fmaf(x, a_src[lane * 4 + k], s1);
        s2 = fmaf(x, a_dst[lane * 4 + k], s2);
    }
#pragma unroll
    for (int off = 1; off < 16; off <<= 1) {
        s1 += __shfl_xor(s1, off);
        s2 += __shfl_xor(s2, off);
    }
    if ((lane & 15) == 0) {
        scores[(size_t)wid * 8 + (lane >> 4)] = s1;
        scores[(size_t)wid * 8 + 4 + (lane >> 4)] = s2;
    }
}

// One thread per (b,h): full 7x7 leaky-relu + mask + top-3 + softmax.
template<int WRITE_ATTN>
__global__ __launch_bounds__(256)
void alpha_k(const float* __restrict__ scores, const float* __restrict__ em2,
             float* __restrict__ alpha, float* __restrict__ attn_out)
{
    const int t = blockIdx.x * 256 + threadIdx.x;
    const int b = t >> 2;
    const int h = t & 3;

    float ssrc[7], sdst[7];
#pragma unroll
    for (int n = 0; n < 7; ++n) {
        ssrc[n] = scores[(size_t)(b * 7 + n) * 8 + h];
        sdst[n] = scores[(size_t)(b * 7 + n) * 8 + 4 + h];
    }

    float al[49];
#pragma unroll
    for (int i = 0; i < 7; ++i) {
        float e[7];
#pragma unroll
        for (int j = 0; j < 7; ++j) {
            float v = ssrc[i] + sdst[j];
            v = fmaxf(v, 0.2f * v);
            e[j] = fmaf(v, em2[(i * 7 + j) * 2], em2[(i * 7 + j) * 2 + 1]);
        }
        float a1 = -3e38f, b1 = -3e38f, c1 = -3e38f;
#pragma unroll
        for (int j = 0; j < 7; ++j) {
            float v = e[j];
            float t2 = fminf(a1, v); a1 = fmaxf(a1, v);
            float t3 = fminf(b1, t2); b1 = fmaxf(b1, t2);
            c1 = fmaxf(c1, t3);
        }
        float psum = 0.f;
        float p[7];
#pragma unroll
        for (int j = 0; j < 7; ++j) {
            float qv = (e[j] >= c1) ? __expf(e[j] - a1) : 0.f;
            p[j] = qv; psum += qv;
        }
        float inv = 1.f / psum;
#pragma unroll
        for (int j = 0; j < 7; ++j) al[i * 7 + j] = p[j] * inv;
    }

    float* ap = alpha + (size_t)t * 49;
#pragma unroll
    for (int j = 0; j < 49; ++j) ap[j] = al[j];

    if (WRITE_ATTN) {
#pragma unroll
        for (int j = 0; j < 49; ++j) {
            float m = al[j];
            m += __shfl_xor(m, 1);
            m += __shfl_xor(m, 2);
            if (h == 0) attn_out[(size_t)b * 49 + j] = 0.25f * m;
        }
    }
}

// PV + residual + LN + relu. One wave per batch element; lane owns 4 cols.
__global__ __launch_bounds__(256)
void gat_apply_k(const u16* __restrict__ hh, int ld_hh,
                 const u16* __restrict__ resid, int ld_res, int res_off,
                 const float* __restrict__ alpha,
                 const float* __restrict__ ln_w, const float* __restrict__ ln_b,
                 u16* __restrict__ outp, int out_bs)
{
    const int t = threadIdx.x;
    const int b = blockIdx.x * 4 + (t >> 6);
    const int l = t & 63;
    const int c = l * 4;
    const int h = l >> 4;
    const size_t rowbase = (size_t)b * 7;

    float hv[7][4];
#pragma unroll
    for (int n = 0; n < 7; ++n) {
        u16x4 qv = *(const u16x4*)&hh[(rowbase + n) * ld_hh + c];
#pragma unroll
        for (int k = 0; k < 4; ++k) hv[n][k] = bf2f(qv[k]);
    }

    const float* ap = alpha + ((size_t)b * 4 + h) * 49;
    float4 lw = *(const float4*)&ln_w[c];
    float4 lb = *(const float4*)&ln_b[c];

#pragma unroll
    for (int i = 0; i < 7; ++i) {
        float a0 = ap[i * 7 + 0], a1 = ap[i * 7 + 1], a2 = ap[i * 7 + 2],
              a3 = ap[i * 7 + 3], a4 = ap[i * 7 + 4], a5 = ap[i * 7 + 5],
              a6 = ap[i * 7 + 6];
        u16x4 rr = *(const u16x4*)&resid[(rowbase + i) * ld_res + res_off + c];
        float x[4];
#pragma unroll
        for (int k = 0; k < 4; ++k) {
            float pv = a0 * hv[0][k];
            pv = fmaf(a1, hv[1][k], pv);
            pv = fmaf(a2, hv[2][k], pv);
            pv = fmaf(a3, hv[3][k], pv);
            pv = fmaf(a4, hv[4][k], pv);
            pv = fmaf(a5, hv[5][k], pv);
            pv = fmaf(a6, hv[6][k], pv);
            x[k] = pv + bf2f(rr[k]);
        }
        float s1 = (x[0] + x[1]) + (x[2] + x[3]);
        float s2 = fmaf(x[0], x[0], x[1] * x[1]) + fmaf(x[2], x[2], x[3] * x[3]);
#pragma unroll
        for (int off = 32; off > 0; off >>= 1) {
            s1 += __shfl_xor(s1, off);
            s2 += __shfl_xor(s2, off);
        }
        float mu  = s1 * (1.f / 256.f);
        float var = fmaxf(s2 * (1.f / 256.f) - mu * mu, 0.f);
        float inv = rsqrtf(var + 1e-5f);
        u16x4 o;
        o[0] = f2bf(fmaxf((x[0] - mu) * inv * lw.x + lb.x, 0.f));
        o[1] = f2bf(fmaxf((x[1] - mu) * inv * lw.y + lb.y, 0.f));
        o[2] = f2bf(fmaxf((x[2] - mu) * inv * lw.z + lb.z, 0.f));
        o[3] = f2bf(fmaxf((x[3] - mu) * inv * lw.w + lb.w, 0.f));
        *(u16x4*)&outp[(size_t)b * out_bs + i * 256 + c] = o;
    }
}

// weight transpose/cast + bias fuse + edge_mask. Wt3 padded to 128 rows.
__global__ __launch_bounds__(256)
void prep_k(const float* __restrict__ W1, const float* __restrict__ skip_w, const float* __restrict__ W2,
            const float* __restrict__ base_w1, const float* __restrict__ reg_w1, const float* __restrict__ res_w1,
            const float* __restrict__ skip_b, const float* __restrict__ base_b1, const float* __restrict__ reg_b1,
            const float* __restrict__ res_b1, const float* __restrict__ edge_logits,
            u16* __restrict__ Wt1, u16* __restrict__ Wt2, u16* __restrict__ Wt3,
            float* __restrict__ bias1, float* __restrict__ bias3,
            float* __restrict__ em2, float* __restrict__ em_out)
{
    int idx = blockIdx.x * 256 + threadIdx.x;
    if (idx < 512 * 256) {            // Wt1[n][k] = [W1|skip_w][k][n]
        int n = idx >> 8, k = idx & 255;
        float v = (n < 256) ? W1[k * 256 + n] : skip_w[k * 256 + (n - 256)];
        Wt1[n * 256 + k] = f2bf(v); return;
    }
    idx -= 512 * 256;
    if (idx < 256 * 256) {
        int n = idx >> 8, k = idx & 255;
        Wt2[n * 256 + k] = f2bf(W2[k * 256 + n]); return;
    }
    idx -= 256 * 256;
    if (idx < 128 * 1920) {           // Wt3 rows 80..127 zero
        int n = idx / 1920, k = idx % 1920;
        float v = (n < 32) ? base_w1[k * 32 + n]
                : (n < 64) ? reg_w1[k * 32 + (n - 32)]
                : (n < 80) ? res_w1[k * 16 + (n - 64)] : 0.f;
        Wt3[n * 1920 + k] = f2bf(v); return;
    }
    idx -= 128 * 1920;
    if (idx < 512) { bias1[idx] = (idx < 256) ? 0.f : skip_b[idx - 256]; return; }
    idx -= 512;
    if (idx < 80) {
        bias3[idx] = (idx < 32) ? base_b1[idx] : (idx < 64) ? reg_b1[idx - 32] : res_b1[idx - 64];
        return;
    }
    idx -= 80;
    if (idx < 49) {
        int i = idx / 7, j = idx % 7;
        float s = 1.f / (1.f + __expf(-edge_logits[idx]));
        float m = (i == j) ? 1.f : s;
        em2[idx * 2] = m;
        em2[idx * 2 + 1] = (1.f - m) * (-1e9f);
        em_out[idx] = m;
    }
}

__global__ __launch_bounds__(256)
void ctx_k(const float* __restrict__ ctx, u16* __restrict__ comb)
{
    int idx = blockIdx.x * 256 + threadIdx.x;   // B*128
    int b = idx >> 7, cc = idx & 127;
    comb[(size_t)b * 1920 + 1792 + cc] = f2bf(ctx[idx]);
}

// Heads; ho = 4 split-K partial slices (stride B*80), summed here.
__global__ __launch_bounds__(256)
void head_finish(const float* __restrict__ ho,
                 const float* __restrict__ bp, const float* __restrict__ rf,
                 const float* __restrict__ bw2, const float* __restrict__ bb2,
                 const float* __restrict__ rw2, const float* __restrict__ rb2,
                 const float* __restrict__ gw1, const float* __restrict__ gb1,
                 const float* __restrict__ gw2, const float* __restrict__ gb2,
                 const float* __restrict__ resw2, const float* __restrict__ resb2,
                 float* __restrict__ out_pred, float* __restrict__ out_w, float* __restrict__ out_gate, int B)
{
    int b = blockIdx.x * 256 + threadIdx.x;
    if (b >= B) return;
    const size_t ss = (size_t)B * 80;
    const float* p0 = ho + (size_t)b * 80;
    float o[80];
#pragma unroll 16
    for (int k = 0; k < 80; ++k)
        o[k] = (p0[k] + p0[ss + k]) + (p0[2 * ss + k] + p0[3 * ss + k]);

    float z0 = bb2[0], z1 = bb2[1];
#pragma unroll 8
    for (int k = 0; k < 32; ++k) { float v = fmaxf(o[k], 0.f); z0 += v * bw2[k * 2]; z1 += v * bw2[k * 2 + 1]; }
    float mz = fmaxf(z0, z1); float e0 = __expf(z0 - mz), e1 = __expf(z1 - mz); float inv = 1.f / (e0 + e1);
    float wb0 = e0 * inv, wb1 = e1 * inv;

    z0 = rb2[0]; z1 = rb2[1];
#pragma unroll 8
    for (int k = 0; k < 32; ++k) { float v = fmaxf(o[32 + k], 0.f); z0 += v * rw2[k * 2]; z1 += v * rw2[k * 2 + 1]; }
    mz = fmaxf(z0, z1); e0 = __expf(z0 - mz); e1 = __expf(z1 - mz); inv = 1.f / (e0 + e1);
    float wr0 = e0 * inv, wr1 = e1 * inv;

    float g = gb2[0];
#pragma unroll
    for (int j = 0; j < 8; ++j) {
        float a = gb1[j];
#pragma unroll
        for (int i = 0; i < 3; ++i) a += rf[(size_t)b * 3 + i] * gw1[i * 8 + j];
        g += fast_tanh(a) * gw2[j];
    }
    float gg = 1.f / (1.f + __expf(-g));
    float w0 = (1.f - gg) * wb0 + gg * wr0;
    float w1 = (1.f - gg) * wb1 + gg * wr1;
    float pred = w0 * bp[(size_t)b * 2] + w1 * bp[(size_t)b * 2 + 1];
    float r = resb2[0];
#pragma unroll 8
    for (int k = 0; k < 16; ++k) r += fast_tanh(o[64 + k]) * resw2[k];
    pred = fmaxf(pred + r * 0.05f, 0.05f);
    out_pred[b] = pred;
    out_w[(size_t)b * 2] = w0; out_w[(size_t)b * 2 + 1] = w1;
    out_gate[b] = gg;
}

extern "C" void kernel_launch(void* const* d_in, const int* in_sizes, int n_in,
                              void* d_out, int out_size, void* d_ws, size_t ws_size,
                              hipStream_t stream)
{
    const int B = in_sizes[1] / 128;     // context is (B,128)
    const int Mbig = B * 7;

    const float* node_feats   = (const float*)d_in[0];
    const float* context      = (const float*)d_in[1];
    const float* base_preds   = (const float*)d_in[2];
    const float* regime_feats = (const float*)d_in[3];
    const float* edge_logits  = (const float*)d_in[4];
    const float* W1      = (const float*)d_in[5];
    const float* a_src1  = (const float*)d_in[6];
    const float* a_dst1  = (const float*)d_in[7];
    const float* W2      = (const float*)d_in[8];
    const float* a_src2  = (const float*)d_in[9];
    const float* a_dst2  = (const float*)d_in[10];
    const float* ln1_w   = (const float*)d_in[11];
    const float* ln1_b   = (const float*)d_in[12];
    const float* ln2_w   = (const float*)d_in[13];
    const float* ln2_b   = (const float*)d_in[14];
    const float* skip_w  = (const float*)d_in[15];
    const float* skip_b  = (const float*)d_in[16];
    const float* base_w1 = (const float*)d_in[17];
    const float* base_b1 = (const float*)d_in[18];
    const float* base_w2 = (const float*)d_in[19];
    const float* base_b2 = (const float*)d_in[20];
    const float* reg_w1  = (const float*)d_in[21];
    const float* reg_b1  = (const float*)d_in[22];
    const float* reg_w2  = (const float*)d_in[23];
    const float* reg_b2  = (const float*)d_in[24];
    const float* gate_w1 = (const float*)d_in[25];
    const float* gate_b1 = (const float*)d_in[26];
    const float* gate_w2 = (const float*)d_in[27];
    const float* gate_b2 = (const float*)d_in[28];
    const float* res_w1  = (const float*)d_in[29];
    const float* res_b1  = (const float*)d_in[30];
    const float* res_w2  = (const float*)d_in[31];
    const float* res_b2  = (const float*)d_in[32];

    // workspace layout (bytes)
    char* ws = (char*)d_ws;
    size_t off = 0;
    u16* hs1 = (u16*)(ws + off);                       // [h1_pre|skip] Mbig x 512 bf16
    u16* hh2 = (u16*)(ws + off);                       // reuse after GAT1: Mbig x 256 bf16
    off += (size_t)Mbig * 512 * 2;
    u16* hbuf = (u16*)(ws + off);  off += (size_t)Mbig * 256 * 2;   // h: Mbig x 256 bf16
    u16* comb = (u16*)(ws + off);  off += (size_t)B * 1920 * 2;     // combined: B x 1920 bf16
    u16* nf_bf = comb;             // A1 bf16 aliases comb (dead until step 9)
    float* headout = (float*)(ws + off); off += (size_t)4 * B * 80 * 4; // 4 split-K slices
    u16* Wt1 = (u16*)(ws + off); off += 512 * 256 * 2;
    u16* Wt2 = (u16*)(ws + off); off += 256 * 256 * 2;
    u16* Wt3 = (u16*)(ws + off); off += (size_t)128 * 1920 * 2;     // padded to 128 rows
    float* bias1 = (float*)(ws + off); off += 512 * 4;
    float* bias3 = (float*)(ws + off); off += 128 * 4;
    float* em2   = (float*)(ws + off); off += 128 * 4;
    float* scoresb = (float*)(ws + off); off += (size_t)Mbig * 8 * 4;   // row scores f32
    float* alphab  = (float*)(ws + off); off += (size_t)B * 4 * 49 * 4; // alpha f32

    float* out_pred = (float*)d_out;
    float* out_w    = out_pred + B;
    float* out_gate = out_pred + 3 * (size_t)B;
    float* out_em   = out_pred + 4 * (size_t)B;
    float* out_attn = out_pred + 4 * (size_t)B + 49;

    const int B4blocks = (B * 4) / 256;

    // 0. node_feats f32 -> bf16 (HBM-bound streaming pass)
    {
        int n8 = Mbig * 256 / 8;
        precast_k<<<dim3((n8 + 255) / 256), dim3(256), 0, stream>>>(node_feats, nf_bf, n8);
    }

    // 1. weight prep + edge mask
    prep_k<<<dim3(1731), dim3(256), 0, stream>>>(W1, skip_w, W2, base_w1, reg_w1, res_w1,
        skip_b, base_b1, reg_b1, res_b1, edge_logits, Wt1, Wt2, Wt3, bias1, bias3, em2, out_em);

    // 2. GEMM1: nf_bf @ [W1|skip_w] -> hs1 (bf16), bias=[0|skip_b]
    gemm_k<1, 0, 0><<<dim3((Mbig / 128) * 4, 1), dim3(256), 0, stream>>>(
        nf_bf, Wt1, bias1, (void*)hs1, Mbig, 512, 256, 256, 512, 4, 256);

    // 3. scores from h1 (= hs1 cols 0..255)
    score_k<<<dim3(Mbig / 4), dim3(256), 0, stream>>>(hs1, 512, a_src1, a_dst1, scoresb, Mbig);

    // 4. alpha for GAT1
    alpha_k<0><<<dim3(B4blocks), dim3(256), 0, stream>>>(scoresb, em2, alphab, (float*)nullptr);

    // 5. GAT1 apply: PV + skip-resid + LN1 + relu -> hbuf
    gat_apply_k<<<dim3(B / 4), dim3(256), 0, stream>>>(
        hs1, 512, hs1, 512, 256, alphab, ln1_w, ln1_b, hbuf, 1792);

    // 6. GEMM2: h @ W2 -> hh2 (reuses hs1 region)
    gemm_k<0, 0, 0><<<dim3((Mbig / 128) * 2, 1), dim3(256), 0, stream>>>(
        hbuf, Wt2, (const float*)nullptr, (void*)hh2, Mbig, 256, 256, 256, 256, 2, 256);

    // 7. scores from h2
    score_k<<<dim3(Mbig / 4), dim3(256), 0, stream>>>(hh2, 256, a_src2, a_dst2, scoresb, Mbig);

    // 8. alpha for GAT2 (+ attn mean output)
    alpha_k<1><<<dim3(B4blocks), dim3(256), 0, stream>>>(scoresb, em2, alphab, out_attn);

    // 9. GAT2 apply: PV + h-resid + LN2 + relu -> comb[:, :1792]
    gat_apply_k<<<dim3(B / 4), dim3(256), 0, stream>>>(
        hh2, 256, hbuf, 256, 0, alphab, ln2_w, ln2_b, comb, 1920);

    // 10. context -> comb[:, 1792:]
    ctx_k<<<dim3(B * 128 / 256), dim3(256), 0, stream>>>(context, comb);

    // 11. GEMM3: comb @ padded-Wt3 + bias -> 4 partial slices (split-K x4, no memset)
    gemm_k<1, 1, 1><<<dim3(B / 128, 4), dim3(256), 0, stream>>>(
        comb, Wt3, bias3, (void*)headout, B, 80, 1920, 1920, 80, 1, 480);

    // 12. heads -> pred, weights, gate (sums the 4 partials)
    head_finish<<<dim3((B + 255) / 256), dim3(256), 0, stream>>>(
        headout, base_preds, regime_feats, base_w2, base_b2, reg_w2, reg_b2,
        gate_w1, gate_b1, gate_w2, gate_b2, res_w2, res_b2, out_pred, out_w, out_gate, B);
}

// Round 11
// 289.068 us; speedup vs baseline: 1.0822x; 1.0419x over previous
//
#include <hip/hip_runtime.h>
#include <hip/hip_bf16.h>

typedef unsigned short u16;
typedef __attribute__((ext_vector_type(8))) short bfrag8;
typedef __attribute__((ext_vector_type(8))) unsigned short u16x8;
typedef __attribute__((ext_vector_type(4))) unsigned short u16x4;
typedef __attribute__((ext_vector_type(4))) float f32x4;

__device__ __forceinline__ float bf2f(u16 u) {
    union { unsigned int i; float f; } v; v.i = ((unsigned int)u) << 16; return v.f;
}
__device__ __forceinline__ u16 f2bf(float f) {
    union { __hip_bfloat16 h; u16 u; } cv;
    cv.h = __float2bfloat16(f);
    return cv.u;
}
__device__ __forceinline__ float fast_tanh(float x) {
    float e = __expf(2.f * x);
    return (e - 1.f) / (e + 1.f);
}

#define TILE_M 128
#define TILE_N 128
#define TILE_K 32

#define GLOAD_LDS16(g, l) \
    __builtin_amdgcn_global_load_lds( \
        (const __attribute__((address_space(1))) void*)(g), \
        (__attribute__((address_space(3))) void*)(l), 16, 0, 0)

// C(M,N) = A(M,K)bf16 @ Wt(N,K)^T (+bias at kc==0). m97 loop + 2-deep
// global_load_lds double-buffer + counted vmcnt(4) (next buffer's 4 DMAs stay
// in flight across the MFMA phase). XCD swizzle (m204).
// C_MODE: 0 = bf16 store, 1 = f32 store at slice kc*M*ldc (split-K partials).
template<int HAS_BIAS, int C_MODE, int NGUARD>
__global__ __launch_bounds__(256)
void gemm_k(const u16* __restrict__ A, const u16* __restrict__ Bt,
            const float* __restrict__ bias, void* __restrict__ Cp,
            int M, int N, int K, int lda, int ldc, int nt, int kchunk)
{
    __shared__ u16 As[2][TILE_M][TILE_K];   // 2 x 8 KB
    __shared__ u16 Bs[2][TILE_N][TILE_K];

    const int nwg = gridDim.x;
    const int q = nwg >> 3, r = nwg & 7;
    const int xcd = blockIdx.x & 7, pos = blockIdx.x >> 3;
    const int wg = (xcd < r ? xcd * (q + 1) : r * (q + 1) + (xcd - r) * q) + pos;
    const int m0 = (wg / nt) * TILE_M;
    const int n0 = (wg % nt) * TILE_N;

    const int kc   = blockIdx.y;
    const int kbeg = kc * kchunk;
    const int kend = (kbeg + kchunk < K) ? kbeg + kchunk : K;

    const int t    = threadIdx.x;
    const int lane = t & 63;
    const int w    = t >> 6;
    const int wm   = (w >> 1) * 64;
    const int wn   = (w & 1) * 64;
    const int lr   = lane & 15;
    const int kg   = (lane >> 4) * 8;

    const int lrow = lane >> 2;          // 0..15
    const int lcol = (lane & 3) * 8;     // 0,8,16,24
    const u16* gA0 = A  + (size_t)(m0 + 32 * w + lrow) * lda + lcol;
    const u16* gA1 = gA0 + (size_t)16 * lda;
    const u16* gB0 = Bt + (size_t)(n0 + 32 * w + lrow) * K + lcol;
    const u16* gB1 = gB0 + (size_t)16 * K;
    char* lA = (char*)&As[0][0][0] + w * 2048;   // + buf*8192
    char* lB = (char*)&Bs[0][0][0] + w * 2048;

    f32x4 acc[4][4];
#pragma unroll
    for (int i = 0; i < 4; ++i)
#pragma unroll
        for (int j = 0; j < 4; ++j) acc[i][j] = (f32x4){0.f, 0.f, 0.f, 0.f};

#define ISSUE(bufo, k0v) { \
        GLOAD_LDS16(gA0 + (k0v), lA + (bufo)); \
        GLOAD_LDS16(gA1 + (k0v), lA + 1024 + (bufo)); \
        GLOAD_LDS16(gB0 + (k0v), lB + (bufo)); \
        GLOAD_LDS16(gB1 + (k0v), lB + 1024 + (bufo)); \
    }

    ISSUE(0, kbeg)
    int buf = 0;
    for (int k0 = kbeg; k0 < kend; k0 += TILE_K) {
        const bool more = (k0 + TILE_K) < kend;
        if (more) {
            ISSUE((buf ^ 1) * 8192, k0 + TILE_K);             // 4 new in flight
            asm volatile("s_waitcnt vmcnt(4)" ::: "memory");  // wait cur buf's 4
        } else {
            asm volatile("s_waitcnt vmcnt(0)" ::: "memory");
        }
        __syncthreads();

        bfrag8 af[4], bfr[4];
#pragma unroll
        for (int mi = 0; mi < 4; ++mi) af[mi]  = *(const bfrag8*)&As[buf][wm + mi * 16 + lr][kg];
#pragma unroll
        for (int ni = 0; ni < 4; ++ni) bfr[ni] = *(const bfrag8*)&Bs[buf][wn + ni * 16 + lr][kg];
#pragma unroll
        for (int mi = 0; mi < 4; ++mi)
#pragma unroll
            for (int ni = 0; ni < 4; ++ni)
                acc[mi][ni] = __builtin_amdgcn_mfma_f32_16x16x32_bf16(af[mi], bfr[ni], acc[mi][ni], 0, 0, 0);

        __syncthreads();   // all waves done reading buf before its next DMA
        buf ^= 1;
    }
#undef ISSUE

    float* Cf = (float*)Cp + (size_t)kc * M * ldc;   // split-K partial slice
#pragma unroll
    for (int mi = 0; mi < 4; ++mi) {
#pragma unroll
        for (int ni = 0; ni < 4; ++ni) {
            int col = n0 + wn + ni * 16 + lr;
            if (!NGUARD || col < N) {
                int row = m0 + wm + mi * 16 + (lane >> 4) * 4;
                float bv = 0.f;
                if (HAS_BIAS && kc == 0) bv = bias[col];
#pragma unroll
                for (int rr = 0; rr < 4; ++rr) {
                    float v = acc[mi][ni][rr] + bv;
                    if (C_MODE == 0) ((u16*)Cp)[(size_t)(row + rr) * ldc + col] = f2bf(v);
                    else             Cf[(size_t)(row + rr) * ldc + col] = v;
                }
            }
        }
    }
}

// f32 -> bf16 streaming cast (HBM-bound), 8 elems/thread.
__global__ __launch_bounds__(256)
void precast_k(const float* __restrict__ in, u16* __restrict__ out, int n8)
{
    int i = blockIdx.x * 256 + threadIdx.x;
    if (i >= n8) return;
    const float4* p = (const float4*)(in + (size_t)i * 8);
    float4 a = p[0], b = p[1];
    u16x8 v;
    v[0] = f2bf(a.x); v[1] = f2bf(a.y); v[2] = f2bf(a.z); v[3] = f2bf(a.w);
    v[4] = f2bf(b.x); v[5] = f2bf(b.y); v[6] = f2bf(b.z); v[7] = f2bf(b.w);
    *(u16x8*)(out + (size_t)i * 8) = v;
}

// scores[row][8] = [s_src h0..3, s_dst h0..3]; one wave per row of h (bf16).
__global__ __launch_bounds__(256)
void score_k(const u16* __restrict__ hs, int ld,
             const float* __restrict__ a_src, const float* __restrict__ a_dst,
             float* __restrict__ scores, int Mrows)
{
    const int wid  = blockIdx.x * 4 + (threadIdx.x >> 6);
    const int lane = threadIdx.x & 63;
    if (wid >= Mrows) return;
    const u16* hp = hs + (size_t)wid * ld + lane * 4;
    u16x4 xv = *(const u16x4*)hp;
    float s1 = 0.f, s2 = 0.f;
#pragma unroll
    for (int k = 0; k < 4; ++k) {
        float x = bf2f(xv[k]);
        s1 = fmaf(x, a_src[lane * 4 + k], s1);
        s2 = fmaf(x, a_dst[lane * 4 + k], s2);
    }
#pragma unroll
    for (int off = 1; off < 16; off <<= 1) {
        s1 += __shfl_xor(s1, off);
        s2 += __shfl_xor(s2, off);
    }
    if ((lane & 15) == 0) {
        scores[(size_t)wid * 8 + (lane >> 4)] = s1;
        scores[(size_t)wid * 8 + 4 + (lane >> 4)] = s2;
    }
}

// One thread per (b,h): full 7x7 leaky-relu + mask + top-3 + softmax.
template<int WRITE_ATTN>
__global__ __launch_bounds__(256)
void alpha_k(const float* __restrict__ scores, const float* __restrict__ em2,
             float* __restrict__ alpha, float* __restrict__ attn_out)
{
    const int t = blockIdx.x * 256 + threadIdx.x;
    const int b = t >> 2;
    const int h = t & 3;

    float ssrc[7], sdst[7];
#pragma unroll
    for (int n = 0; n < 7; ++n) {
        ssrc[n] = scores[(size_t)(b * 7 + n) * 8 + h];
        sdst[n] = scores[(size_t)(b * 7 + n) * 8 + 4 + h];
    }

    float al[49];
#pragma unroll
    for (int i = 0; i < 7; ++i) {
        float e[7];
#pragma unroll
        for (int j = 0; j < 7; ++j) {
            float v = ssrc[i] + sdst[j];
            v = fmaxf(v, 0.2f * v);
            e[j] = fmaf(v, em2[(i * 7 + j) * 2], em2[(i * 7 + j) * 2 + 1]);
        }
        float a1 = -3e38f, b1 = -3e38f, c1 = -3e38f;
#pragma unroll
        for (int j = 0; j < 7; ++j) {
            float v = e[j];
            float t2 = fminf(a1, v); a1 = fmaxf(a1, v);
            float t3 = fminf(b1, t2); b1 = fmaxf(b1, t2);
            c1 = fmaxf(c1, t3);
        }
        float psum = 0.f;
        float p[7];
#pragma unroll
        for (int j = 0; j < 7; ++j) {
            float qv = (e[j] >= c1) ? __expf(e[j] - a1) : 0.f;
            p[j] = qv; psum += qv;
        }
        float inv = 1.f / psum;
#pragma unroll
        for (int j = 0; j < 7; ++j) al[i * 7 + j] = p[j] * inv;
    }

    float* ap = alpha + (size_t)t * 49;
#pragma unroll
    for (int j = 0; j < 49; ++j) ap[j] = al[j];

    if (WRITE_ATTN) {
#pragma unroll
        for (int j = 0; j < 49; ++j) {
            float m = al[j];
            m += __shfl_xor(m, 1);
            m += __shfl_xor(m, 2);
            if (h == 0) attn_out[(size_t)b * 49 + j] = 0.25f * m;
        }
    }
}

// PV + residual + LN + relu. One wave per batch element; lane owns 4 cols.
__global__ __launch_bounds__(256)
void gat_apply_k(const u16* __restrict__ hh, int ld_hh,
                 const u16* __restrict__ resid, int ld_res, int res_off,
                 const float* __restrict__ alpha,
                 const float* __restrict__ ln_w, const float* __restrict__ ln_b,
                 u16* __restrict__ outp, int out_bs)
{
    const int t = threadIdx.x;
    const int b = blockIdx.x * 4 + (t >> 6);
    const int l = t & 63;
    const int c = l * 4;
    const int h = l >> 4;
    const size_t rowbase = (size_t)b * 7;

    float hv[7][4];
#pragma unroll
    for (int n = 0; n < 7; ++n) {
        u16x4 qv = *(const u16x4*)&hh[(rowbase + n) * ld_hh + c];
#pragma unroll
        for (int k = 0; k < 4; ++k) hv[n][k] = bf2f(qv[k]);
    }

    const float* ap = alpha + ((size_t)b * 4 + h) * 49;
    float4 lw = *(const float4*)&ln_w[c];
    float4 lb = *(const float4*)&ln_b[c];

#pragma unroll
    for (int i = 0; i < 7; ++i) {
        float a0 = ap[i * 7 + 0], a1 = ap[i * 7 + 1], a2 = ap[i * 7 + 2],
              a3 = ap[i * 7 + 3], a4 = ap[i * 7 + 4], a5 = ap[i * 7 + 5],
              a6 = ap[i * 7 + 6];
        u16x4 rr = *(const u16x4*)&resid[(rowbase + i) * ld_res + res_off + c];
        float x[4];
#pragma unroll
        for (int k = 0; k < 4; ++k) {
            float pv = a0 * hv[0][k];
            pv = fmaf(a1, hv[1][k], pv);
            pv = fmaf(a2, hv[2][k], pv);
            pv = fmaf(a3, hv[3][k], pv);
            pv = fmaf(a4, hv[4][k], pv);
            pv = fmaf(a5, hv[5][k], pv);
            pv = fmaf(a6, hv[6][k], pv);
            x[k] = pv + bf2f(rr[k]);
        }
        float s1 = (x[0] + x[1]) + (x[2] + x[3]);
        float s2 = fmaf(x[0], x[0], x[1] * x[1]) + fmaf(x[2], x[2], x[3] * x[3]);
#pragma unroll
        for (int off = 32; off > 0; off >>= 1) {
            s1 += __shfl_xor(s1, off);
            s2 += __shfl_xor(s2, off);
        }
        float mu  = s1 * (1.f / 256.f);
        float var = fmaxf(s2 * (1.f / 256.f) - mu * mu, 0.f);
        float inv = rsqrtf(var + 1e-5f);
        u16x4 o;
        o[0] = f2bf(fmaxf((x[0] - mu) * inv * lw.x + lb.x, 0.f));
        o[1] = f2bf(fmaxf((x[1] - mu) * inv * lw.y + lb.y, 0.f));
        o[2] = f2bf(fmaxf((x[2] - mu) * inv * lw.z + lb.z, 0.f));
        o[3] = f2bf(fmaxf((x[3] - mu) * inv * lw.w + lb.w, 0.f));
        *(u16x4*)&outp[(size_t)b * out_bs + i * 256 + c] = o;
    }
}

// weight transpose/cast + bias fuse + edge_mask. Wt3 padded to 128 rows.
__global__ __launch_bounds__(256)
void prep_k(const float* __restrict__ W1, const float* __restrict__ skip_w, const float* __restrict__ W2,
            const float* __restrict__ base_w1, const float* __restrict__ reg_w1, const float* __restrict__ res_w1,
            const float* __restrict__ skip_b, const float* __restrict__ base_b1, const float* __restrict__ reg_b1,
            const float* __restrict__ res_b1, const float* __restrict__ edge_logits,
            u16* __restrict__ Wt1, u16* __restrict__ Wt2, u16* __restrict__ Wt3,
            float* __restrict__ bias1, float* __restrict__ bias3,
            float* __restrict__ em2, float* __restrict__ em_out)
{
    int idx = blockIdx.x * 256 + threadIdx.x;
    if (idx < 512 * 256) {            // Wt1[n][k] = [W1|skip_w][k][n]
        int n = idx >> 8, k = idx & 255;
        float v = (n < 256) ? W1[k * 256 + n] : skip_w[k * 256 + (n - 256)];
        Wt1[n * 256 + k] = f2bf(v); return;
    }
    idx -= 512 * 256;
    if (idx < 256 * 256) {
        int n = idx >> 8, k = idx & 255;
        Wt2[n * 256 + k] = f2bf(W2[k * 256 + n]); return;
    }
    idx -= 256 * 256;
    if (idx < 128 * 1920) {           // Wt3 rows 80..127 zero
        int n = idx / 1920, k = idx % 1920;
        float v = (n < 32) ? base_w1[k * 32 + n]
                : (n < 64) ? reg_w1[k * 32 + (n - 32)]
                : (n < 80) ? res_w1[k * 16 + (n - 64)] : 0.f;
        Wt3[n * 1920 + k] = f2bf(v); return;
    }
    idx -= 128 * 1920;
    if (idx < 512) { bias1[idx] = (idx < 256) ? 0.f : skip_b[idx - 256]; return; }
    idx -= 512;
    if (idx < 80) {
        bias3[idx] = (idx < 32) ? base_b1[idx] : (idx < 64) ? reg_b1[idx - 32] : res_b1[idx - 64];
        return;
    }
    idx -= 80;
    if (idx < 49) {
        int i = idx / 7, j = idx % 7;
        float s = 1.f / (1.f + __expf(-edge_logits[idx]));
        float m = (i == j) ? 1.f : s;
        em2[idx * 2] = m;
        em2[idx * 2 + 1] = (1.f - m) * (-1e9f);
        em_out[idx] = m;
    }
}

__global__ __launch_bounds__(256)
void ctx_k(const float* __restrict__ ctx, u16* __restrict__ comb)
{
    int idx = blockIdx.x * 256 + threadIdx.x;   // B*128
    int b = idx >> 7, cc = idx & 127;
    comb[(size_t)b * 1920 + 1792 + cc] = f2bf(ctx[idx]);
}

// Heads; ho = 4 split-K partial slices (stride B*80). R10's float o[80] was
// runtime-indexed under partial unroll -> scratch spill (rule #20), serializing
// 320 HBM-latency loads (125 us, VALUBusy 0.007%). Rewritten: NO arrays —
// stream slices as float4 and accumulate in registers; 64-thread blocks so all
// 256 CUs participate.
__global__ __launch_bounds__(64)
void head_finish(const float* __restrict__ ho,
                 const float* __restrict__ bp, const float* __restrict__ rf,
                 const float* __restrict__ bw2, const float* __restrict__ bb2,
                 const float* __restrict__ rw2, const float* __restrict__ rb2,
                 const float* __restrict__ gw1, const float* __restrict__ gb1,
                 const float* __restrict__ gw2, const float* __restrict__ gb2,
                 const float* __restrict__ resw2, const float* __restrict__ resb2,
                 float* __restrict__ out_pred, float* __restrict__ out_w, float* __restrict__ out_gate, int B)
{
    int b = blockIdx.x * 64 + threadIdx.x;
    if (b >= B) return;
    const size_t ss = (size_t)B * 80;
    const float* p = ho + (size_t)b * 80;

    float z0 = bb2[0], z1 = bb2[1];
#pragma unroll
    for (int j = 0; j < 32; j += 4) {
        float4 a0 = *(const float4*)(p + j);
        float4 a1 = *(const float4*)(p + ss + j);
        float4 a2 = *(const float4*)(p + 2 * ss + j);
        float4 a3 = *(const float4*)(p + 3 * ss + j);
        float v;
        v = fmaxf((a0.x + a1.x) + (a2.x + a3.x), 0.f); z0 = fmaf(v, bw2[2*j+0], z0); z1 = fmaf(v, bw2[2*j+1], z1);
        v = fmaxf((a0.y + a1.y) + (a2.y + a3.y), 0.f); z0 = fmaf(v, bw2[2*j+2], z0); z1 = fmaf(v, bw2[2*j+3], z1);
        v = fmaxf((a0.z + a1.z) + (a2.z + a3.z), 0.f); z0 = fmaf(v, bw2[2*j+4], z0); z1 = fmaf(v, bw2[2*j+5], z1);
        v = fmaxf((a0.w + a1.w) + (a2.w + a3.w), 0.f); z0 = fmaf(v, bw2[2*j+6], z0); z1 = fmaf(v, bw2[2*j+7], z1);
    }
    float mz = fmaxf(z0, z1); float e0 = __expf(z0 - mz), e1 = __expf(z1 - mz); float inv = 1.f / (e0 + e1);
    float wb0 = e0 * inv, wb1 = e1 * inv;

    z0 = rb2[0]; z1 = rb2[1];
#pragma unroll
    for (int j = 0; j < 32; j += 4) {
        float4 a0 = *(const float4*)(p + 32 + j);
        float4 a1 = *(const float4*)(p + ss + 32 + j);
        float4 a2 = *(const float4*)(p + 2 * ss + 32 + j);
        float4 a3 = *(const float4*)(p + 3 * ss + 32 + j);
        float v;
        v = fmaxf((a0.x + a1.x) + (a2.x + a3.x), 0.f); z0 = fmaf(v, rw2[2*j+0], z0); z1 = fmaf(v, rw2[2*j+1], z1);
        v = fmaxf((a0.y + a1.y) + (a2.y + a3.y), 0.f); z0 = fmaf(v, rw2[2*j+2], z0); z1 = fmaf(v, rw2[2*j+3], z1);
        v = fmaxf((a0.z + a1.z) + (a2.z + a3.z), 0.f); z0 = fmaf(v, rw2[2*j+4], z0); z1 = fmaf(v, rw2[2*j+5], z1);
        v = fmaxf((a0.w + a1.w) + (a2.w + a3.w), 0.f); z0 = fmaf(v, rw2[2*j+6], z0); z1 = fmaf(v, rw2[2*j+7], z1);
    }
    mz = fmaxf(z0, z1); e0 = __expf(z0 - mz); e1 = __expf(z1 - mz); inv = 1.f / (e0 + e1);
    float wr0 = e0 * inv, wr1 = e1 * inv;

    float r = resb2[0];
#pragma unroll
    for (int j = 0; j < 16; j += 4) {
        float4 a0 = *(const float4*)(p + 64 + j);
        float4 a1 = *(const float4*)(p + ss + 64 + j);
        float4 a2 = *(const float4*)(p + 2 * ss + 64 + j);
        float4 a3 = *(const float4*)(p + 3 * ss + 64 + j);
        r = fmaf(fast_tanh((a0.x + a1.x) + (a2.x + a3.x)), resw2[j + 0], r);
        r = fmaf(fast_tanh((a0.y + a1.y) + (a2.y + a3.y)), resw2[j + 1], r);
        r = fmaf(fast_tanh((a0.z + a1.z) + (a2.z + a3.z)), resw2[j + 2], r);
        r = fmaf(fast_tanh((a0.w + a1.w) + (a2.w + a3.w)), resw2[j + 3], r);
    }

    float g = gb2[0];
#pragma unroll
    for (int j = 0; j < 8; ++j) {
        float a = gb1[j];
#pragma unroll
        for (int i = 0; i < 3; ++i) a += rf[(size_t)b * 3 + i] * gw1[i * 8 + j];
        g += fast_tanh(a) * gw2[j];
    }
    float gg = 1.f / (1.f + __expf(-g));
    float w0 = (1.f - gg) * wb0 + gg * wr0;
    float w1 = (1.f - gg) * wb1 + gg * wr1;
    float pred = w0 * bp[(size_t)b * 2] + w1 * bp[(size_t)b * 2 + 1];
    pred = fmaxf(pred + r * 0.05f, 0.05f);
    out_pred[b] = pred;
    out_w[(size_t)b * 2] = w0; out_w[(size_t)b * 2 + 1] = w1;
    out_gate[b] = gg;
}

extern "C" void kernel_launch(void* const* d_in, const int* in_sizes, int n_in,
                              void* d_out, int out_size, void* d_ws, size_t ws_size,
                              hipStream_t stream)
{
    const int B = in_sizes[1] / 128;     // context is (B,128)
    const int Mbig = B * 7;

    const float* node_feats   = (const float*)d_in[0];
    const float* context      = (const float*)d_in[1];
    const float* base_preds   = (const float*)d_in[2];
    const float* regime_feats = (const float*)d_in[3];
    const float* edge_logits  = (const float*)d_in[4];
    const float* W1      = (const float*)d_in[5];
    const float* a_src1  = (const float*)d_in[6];
    const float* a_dst1  = (const float*)d_in[7];
    const float* W2      = (const float*)d_in[8];
    const float* a_src2  = (const float*)d_in[9];
    const float* a_dst2  = (const float*)d_in[10];
    const float* ln1_w   = (const float*)d_in[11];
    const float* ln1_b   = (const float*)d_in[12];
    const float* ln2_w   = (const float*)d_in[13];
    const float* ln2_b   = (const float*)d_in[14];
    const float* skip_w  = (const float*)d_in[15];
    const float* skip_b  = (const float*)d_in[16];
    const float* base_w1 = (const float*)d_in[17];
    const float* base_b1 = (const float*)d_in[18];
    const float* base_w2 = (const float*)d_in[19];
    const float* base_b2 = (const float*)d_in[20];
    const float* reg_w1  = (const float*)d_in[21];
    const float* reg_b1  = (const float*)d_in[22];
    const float* reg_w2  = (const float*)d_in[23];
    const float* reg_b2  = (const float*)d_in[24];
    const float* gate_w1 = (const float*)d_in[25];
    const float* gate_b1 = (const float*)d_in[26];
    const float* gate_w2 = (const float*)d_in[27];
    const float* gate_b2 = (const float*)d_in[28];
    const float* res_w1  = (const float*)d_in[29];
    const float* res_b1  = (const float*)d_in[30];
    const float* res_w2  = (const float*)d_in[31];
    const float* res_b2  = (const float*)d_in[32];

    // workspace layout (bytes)
    char* ws = (char*)d_ws;
    size_t off = 0;
    u16* hs1 = (u16*)(ws + off);                       // [h1_pre|skip] Mbig x 512 bf16
    u16* hh2 = (u16*)(ws + off);                       // reuse after GAT1: Mbig x 256 bf16
    off += (size_t)Mbig * 512 * 2;
    u16* hbuf = (u16*)(ws + off);  off += (size_t)Mbig * 256 * 2;   // h: Mbig x 256 bf16
    u16* comb = (u16*)(ws + off);  off += (size_t)B * 1920 * 2;     // combined: B x 1920 bf16
    u16* nf_bf = comb;             // A1 bf16 aliases comb (dead until step 9)
    float* headout = (float*)(ws + off); off += (size_t)4 * B * 80 * 4; // 4 split-K slices
    u16* Wt1 = (u16*)(ws + off); off += 512 * 256 * 2;
    u16* Wt2 = (u16*)(ws + off); off += 256 * 256 * 2;
    u16* Wt3 = (u16*)(ws + off); off += (size_t)128 * 1920 * 2;     // padded to 128 rows
    float* bias1 = (float*)(ws + off); off += 512 * 4;
    float* bias3 = (float*)(ws + off); off += 128 * 4;
    float* em2   = (float*)(ws + off); off += 128 * 4;
    float* scoresb = (float*)(ws + off); off += (size_t)Mbig * 8 * 4;   // row scores f32
    float* alphab  = (float*)(ws + off); off += (size_t)B * 4 * 49 * 4; // alpha f32

    float* out_pred = (float*)d_out;
    float* out_w    = out_pred + B;
    float* out_gate = out_pred + 3 * (size_t)B;
    float* out_em   = out_pred + 4 * (size_t)B;
    float* out_attn = out_pred + 4 * (size_t)B + 49;

    const int B4blocks = (B * 4) / 256;

    // 0. node_feats f32 -> bf16 (HBM-bound streaming pass)
    {
        int n8 = Mbig * 256 / 8;
        precast_k<<<dim3((n8 + 255) / 256), dim3(256), 0, stream>>>(node_feats, nf_bf, n8);
    }

    // 1. weight prep + edge mask
    prep_k<<<dim3(1731), dim3(256), 0, stream>>>(W1, skip_w, W2, base_w1, reg_w1, res_w1,
        skip_b, base_b1, reg_b1, res_b1, edge_logits, Wt1, Wt2, Wt3, bias1, bias3, em2, out_em);

    // 2. GEMM1: nf_bf @ [W1|skip_w] -> hs1 (bf16), bias=[0|skip_b]
    gemm_k<1, 0, 0><<<dim3((Mbig / 128) * 4, 1), dim3(256), 0, stream>>>(
        nf_bf, Wt1, bias1, (void*)hs1, Mbig, 512, 256, 256, 512, 4, 256);

    // 3. scores from h1 (= hs1 cols 0..255)
    score_k<<<dim3(Mbig / 4), dim3(256), 0, stream>>>(hs1, 512, a_src1, a_dst1, scoresb, Mbig);

    // 4. alpha for GAT1
    alpha_k<0><<<dim3(B4blocks), dim3(256), 0, stream>>>(scoresb, em2, alphab, (float*)nullptr);

    // 5. GAT1 apply: PV + skip-resid + LN1 + relu -> hbuf
    gat_apply_k<<<dim3(B / 4), dim3(256), 0, stream>>>(
        hs1, 512, hs1, 512, 256, alphab, ln1_w, ln1_b, hbuf, 1792);

    // 6. GEMM2: h @ W2 -> hh2 (reuses hs1 region)
    gemm_k<0, 0, 0><<<dim3((Mbig / 128) * 2, 1), dim3(256), 0, stream>>>(
        hbuf, Wt2, (const float*)nullptr, (void*)hh2, Mbig, 256, 256, 256, 256, 2, 256);

    // 7. scores from h2
    score_k<<<dim3(Mbig / 4), dim3(256), 0, stream>>>(hh2, 256, a_src2, a_dst2, scoresb, Mbig);

    // 8. alpha for GAT2 (+ attn mean output)
    alpha_k<1><<<dim3(B4blocks), dim3(256), 0, stream>>>(scoresb, em2, alphab, out_attn);

    // 9. GAT2 apply: PV + h-resid + LN2 + relu -> comb[:, :1792]
    gat_apply_k<<<dim3(B / 4), dim3(256), 0, stream>>>(
        hh2, 256, hbuf, 256, 0, alphab, ln2_w, ln2_b, comb, 1920);

    // 10. context -> comb[:, 1792:]
    ctx_k<<<dim3(B * 128 / 256), dim3(256), 0, stream>>>(context, comb);

    // 11. GEMM3: comb @ padded-Wt3 + bias -> 4 partial slices (split-K x4, no memset)
    gemm_k<1, 1, 1><<<dim3(B / 128, 4), dim3(256), 0, stream>>>(
        comb, Wt3, bias3, (void*)headout, B, 80, 1920, 1920, 80, 1, 480);

    // 12. heads -> pred, weights, gate (sums the 4 partials, array-free)
    head_finish<<<dim3((B + 63) / 64), dim3(64), 0, stream>>>(
        headout, base_preds, regime_feats, base_w2, base_b2, reg_w2, reg_b2,
        gate_w1, gate_b1, gate_w2, gate_b2, res_w2, res_b2, out_pred, out_w, out_gate, B);
}

// Round 12
// 284.142 us; speedup vs baseline: 1.1010x; 1.0173x over previous
//
#include <hip/hip_runtime.h>
#include <hip/hip_bf16.h>

typedef unsigned short u16;
typedef __attribute__((ext_vector_type(8))) short bfrag8;
typedef __attribute__((ext_vector_type(8))) unsigned short u16x8;
typedef __attribute__((ext_vector_type(4))) unsigned short u16x4;
typedef __attribute__((ext_vector_type(4))) float f32x4;

__device__ __forceinline__ float bf2f(u16 u) {
    union { unsigned int i; float f; } v; v.i = ((unsigned int)u) << 16; return v.f;
}
__device__ __forceinline__ u16 f2bf(float f) {
    union { __hip_bfloat16 h; u16 u; } cv;
    cv.h = __float2bfloat16(f);
    return cv.u;
}
__device__ __forceinline__ float fast_tanh(float x) {
    float e = __expf(2.f * x);
    return (e - 1.f) / (e + 1.f);
}

#define TILE_M 128
#define TILE_N 128
#define TILE_K 32

#define GLOAD_LDS16(g, l) \
    __builtin_amdgcn_global_load_lds( \
        (const __attribute__((address_space(1))) void*)(g), \
        (__attribute__((address_space(3))) void*)(l), 16, 0, 0)

// C(M,N) = A(M,K)bf16 @ Wt(N,K)^T (+bias at kc==0). m97 loop + 3-buffer
// depth-2 global_load_lds pipeline: tile t+2's DMAs issue before computing
// tile t; vmcnt(8) leaves 8 loads (2 future tiles) in flight — R11's depth-1
// vmcnt(4) gave loads only ~1 phase (~200cy) vs ~500cy latency (GEMM1 stuck
// at 66us, MfmaUtil 17%). Buf t%3 is re-targeted at iter t+1, after iter t's
// trailing barrier -> race-free. XCD swizzle (m204).
// C_MODE: 0 = bf16 store, 1 = f32 store at slice kc*M*ldc (split-K partials).
template<int HAS_BIAS, int C_MODE, int NGUARD>
__global__ __launch_bounds__(256)
void gemm_k(const u16* __restrict__ A, const u16* __restrict__ Bt,
            const float* __restrict__ bias, void* __restrict__ Cp,
            int M, int N, int K, int lda, int ldc, int nt, int kchunk)
{
    __shared__ u16 As[3][TILE_M][TILE_K];   // 3 x 8 KB
    __shared__ u16 Bs[3][TILE_N][TILE_K];

    const int nwg = gridDim.x;
    const int q = nwg >> 3, r = nwg & 7;
    const int xcd = blockIdx.x & 7, pos = blockIdx.x >> 3;
    const int wg = (xcd < r ? xcd * (q + 1) : r * (q + 1) + (xcd - r) * q) + pos;
    const int m0 = (wg / nt) * TILE_M;
    const int n0 = (wg % nt) * TILE_N;

    const int kc    = blockIdx.y;
    const int kbeg  = kc * kchunk;
    const int kend  = (kbeg + kchunk < K) ? kbeg + kchunk : K;
    const int steps = (kend - kbeg) / TILE_K;

    const int t    = threadIdx.x;
    const int lane = t & 63;
    const int w    = t >> 6;
    const int wm   = (w >> 1) * 64;
    const int wn   = (w & 1) * 64;
    const int lr   = lane & 15;
    const int kg   = (lane >> 4) * 8;

    const int lrow = lane >> 2;          // 0..15
    const int lcol = (lane & 3) * 8;     // 0,8,16,24
    const u16* gA0 = A  + (size_t)(m0 + 32 * w + lrow) * lda + lcol;
    const u16* gA1 = gA0 + (size_t)16 * lda;
    const u16* gB0 = Bt + (size_t)(n0 + 32 * w + lrow) * K + lcol;
    const u16* gB1 = gB0 + (size_t)16 * K;
    char* lA = (char*)&As[0][0][0] + w * 2048;   // + buf*8192
    char* lB = (char*)&Bs[0][0][0] + w * 2048;

    f32x4 acc[4][4];
#pragma unroll
    for (int i = 0; i < 4; ++i)
#pragma unroll
        for (int j = 0; j < 4; ++j) acc[i][j] = (f32x4){0.f, 0.f, 0.f, 0.f};

#define ISSUE(bufo, k0v) { \
        GLOAD_LDS16(gA0 + (k0v), lA + (bufo)); \
        GLOAD_LDS16(gA1 + (k0v), lA + 1024 + (bufo)); \
        GLOAD_LDS16(gB0 + (k0v), lB + (bufo)); \
        GLOAD_LDS16(gB1 + (k0v), lB + 1024 + (bufo)); \
    }

    ISSUE(0, kbeg)
    if (steps > 1) ISSUE(8192, kbeg + TILE_K)

    int buf = 0;
    for (int st = 0; st < steps; ++st) {
        if (st + 2 < steps) {
            int nb = buf + 2; if (nb >= 3) nb -= 3;
            ISSUE(nb * 8192, kbeg + (st + 2) * TILE_K);       // 4 new in flight
            asm volatile("s_waitcnt vmcnt(8)" ::: "memory");  // oldest 4 landed
        } else if (st + 1 < steps) {
            asm volatile("s_waitcnt vmcnt(4)" ::: "memory");
        } else {
            asm volatile("s_waitcnt vmcnt(0)" ::: "memory");
        }
        __syncthreads();

        bfrag8 af[4], bfr[4];
#pragma unroll
        for (int mi = 0; mi < 4; ++mi) af[mi]  = *(const bfrag8*)&As[buf][wm + mi * 16 + lr][kg];
#pragma unroll
        for (int ni = 0; ni < 4; ++ni) bfr[ni] = *(const bfrag8*)&Bs[buf][wn + ni * 16 + lr][kg];
#pragma unroll
        for (int mi = 0; mi < 4; ++mi)
#pragma unroll
            for (int ni = 0; ni < 4; ++ni)
                acc[mi][ni] = __builtin_amdgcn_mfma_f32_16x16x32_bf16(af[mi], bfr[ni], acc[mi][ni], 0, 0, 0);

        __syncthreads();   // all waves done reading buf before iter st+1 re-targets it
        ++buf; if (buf == 3) buf = 0;
    }
#undef ISSUE

    float* Cf = (float*)Cp + (size_t)kc * M * ldc;   // split-K partial slice
#pragma unroll
    for (int mi = 0; mi < 4; ++mi) {
#pragma unroll
        for (int ni = 0; ni < 4; ++ni) {
            int col = n0 + wn + ni * 16 + lr;
            if (!NGUARD || col < N) {
                int row = m0 + wm + mi * 16 + (lane >> 4) * 4;
                float bv = 0.f;
                if (HAS_BIAS && kc == 0) bv = bias[col];
#pragma unroll
                for (int rr = 0; rr < 4; ++rr) {
                    float v = acc[mi][ni][rr] + bv;
                    if (C_MODE == 0) ((u16*)Cp)[(size_t)(row + rr) * ldc + col] = f2bf(v);
                    else             Cf[(size_t)(row + rr) * ldc + col] = v;
                }
            }
        }
    }
}

// f32 -> bf16 streaming cast (HBM-bound), 8 elems/thread.
__global__ __launch_bounds__(256)
void precast_k(const float* __restrict__ in, u16* __restrict__ out, int n8)
{
    int i = blockIdx.x * 256 + threadIdx.x;
    if (i >= n8) return;
    const float4* p = (const float4*)(in + (size_t)i * 8);
    float4 a = p[0], b = p[1];
    u16x8 v;
    v[0] = f2bf(a.x); v[1] = f2bf(a.y); v[2] = f2bf(a.z); v[3] = f2bf(a.w);
    v[4] = f2bf(b.x); v[5] = f2bf(b.y); v[6] = f2bf(b.z); v[7] = f2bf(b.w);
    *(u16x8*)(out + (size_t)i * 8) = v;
}

// scores[row][8] = [s_src h0..3, s_dst h0..3]; one wave per row of h (bf16).
__global__ __launch_bounds__(256)
void score_k(const u16* __restrict__ hs, int ld,
             const float* __restrict__ a_src, const float* __restrict__ a_dst,
             float* __restrict__ scores, int Mrows)
{
    const int wid  = blockIdx.x * 4 + (threadIdx.x >> 6);
    const int lane = threadIdx.x & 63;
    if (wid >= Mrows) return;
    const u16* hp = hs + (size_t)wid * ld + lane * 4;
    u16x4 xv = *(const u16x4*)hp;
    float s1 = 0.f, s2 = 0.f;
#pragma unroll
    for (int k = 0; k < 4; ++k) {
        float x = bf2f(xv[k]);
        s1 = fmaf(x, a_src[lane * 4 + k], s1);
        s2 = fmaf(x, a_dst[lane * 4 + k], s2);
    }
#pragma unroll
    for (int off = 1; off < 16; off <<= 1) {
        s1 += __shfl_xor(s1, off);
        s2 += __shfl_xor(s2, off);
    }
    if ((lane & 15) == 0) {
        scores[(size_t)wid * 8 + (lane >> 4)] = s1;
        scores[(size_t)wid * 8 + 4 + (lane >> 4)] = s2;
    }
}

// One thread per (b,h): full 7x7 leaky-relu + mask + top-3 + softmax.
template<int WRITE_ATTN>
__global__ __launch_bounds__(256)
void alpha_k(const float* __restrict__ scores, const float* __restrict__ em2,
             float* __restrict__ alpha, float* __restrict__ attn_out)
{
    const int t = blockIdx.x * 256 + threadIdx.x;
    const int b = t >> 2;
    const int h = t & 3;

    float ssrc[7], sdst[7];
#pragma unroll
    for (int n = 0; n < 7; ++n) {
        ssrc[n] = scores[(size_t)(b * 7 + n) * 8 + h];
        sdst[n] = scores[(size_t)(b * 7 + n) * 8 + 4 + h];
    }

    float al[49];
#pragma unroll
    for (int i = 0; i < 7; ++i) {
        float e[7];
#pragma unroll
        for (int j = 0; j < 7; ++j) {
            float v = ssrc[i] + sdst[j];
            v = fmaxf(v, 0.2f * v);
            e[j] = fmaf(v, em2[(i * 7 + j) * 2], em2[(i * 7 + j) * 2 + 1]);
        }
        float a1 = -3e38f, b1 = -3e38f, c1 = -3e38f;
#pragma unroll
        for (int j = 0; j < 7; ++j) {
            float v = e[j];
            float t2 = fminf(a1, v); a1 = fmaxf(a1, v);
            float t3 = fminf(b1, t2); b1 = fmaxf(b1, t2);
            c1 = fmaxf(c1, t3);
        }
        float psum = 0.f;
        float p[7];
#pragma unroll
        for (int j = 0; j < 7; ++j) {
            float qv = (e[j] >= c1) ? __expf(e[j] - a1) : 0.f;
            p[j] = qv; psum += qv;
        }
        float inv = 1.f / psum;
#pragma unroll
        for (int j = 0; j < 7; ++j) al[i * 7 + j] = p[j] * inv;
    }

    float* ap = alpha + (size_t)t * 49;
#pragma unroll
    for (int j = 0; j < 49; ++j) ap[j] = al[j];

    if (WRITE_ATTN) {
#pragma unroll
        for (int j = 0; j < 49; ++j) {
            float m = al[j];
            m += __shfl_xor(m, 1);
            m += __shfl_xor(m, 2);
            if (h == 0) attn_out[(size_t)b * 49 + j] = 0.25f * m;
        }
    }
}

// PV + residual + LN + relu. One wave per batch element; lane owns 4 cols.
__global__ __launch_bounds__(256)
void gat_apply_k(const u16* __restrict__ hh, int ld_hh,
                 const u16* __restrict__ resid, int ld_res, int res_off,
                 const float* __restrict__ alpha,
                 const float* __restrict__ ln_w, const float* __restrict__ ln_b,
                 u16* __restrict__ outp, int out_bs)
{
    const int t = threadIdx.x;
    const int b = blockIdx.x * 4 + (t >> 6);
    const int l = t & 63;
    const int c = l * 4;
    const int h = l >> 4;
    const size_t rowbase = (size_t)b * 7;

    float hv[7][4];
#pragma unroll
    for (int n = 0; n < 7; ++n) {
        u16x4 qv = *(const u16x4*)&hh[(rowbase + n) * ld_hh + c];
#pragma unroll
        for (int k = 0; k < 4; ++k) hv[n][k] = bf2f(qv[k]);
    }

    const float* ap = alpha + ((size_t)b * 4 + h) * 49;
    float4 lw = *(const float4*)&ln_w[c];
    float4 lb = *(const float4*)&ln_b[c];

#pragma unroll
    for (int i = 0; i < 7; ++i) {
        float a0 = ap[i * 7 + 0], a1 = ap[i * 7 + 1], a2 = ap[i * 7 + 2],
              a3 = ap[i * 7 + 3], a4 = ap[i * 7 + 4], a5 = ap[i * 7 + 5],
              a6 = ap[i * 7 + 6];
        u16x4 rr = *(const u16x4*)&resid[(rowbase + i) * ld_res + res_off + c];
        float x[4];
#pragma unroll
        for (int k = 0; k < 4; ++k) {
            float pv = a0 * hv[0][k];
            pv = fmaf(a1, hv[1][k], pv);
            pv = fmaf(a2, hv[2][k], pv);
            pv = fmaf(a3, hv[3][k], pv);
            pv = fmaf(a4, hv[4][k], pv);
            pv = fmaf(a5, hv[5][k], pv);
            pv = fmaf(a6, hv[6][k], pv);
            x[k] = pv + bf2f(rr[k]);
        }
        float s1 = (x[0] + x[1]) + (x[2] + x[3]);
        float s2 = fmaf(x[0], x[0], x[1] * x[1]) + fmaf(x[2], x[2], x[3] * x[3]);
#pragma unroll
        for (int off = 32; off > 0; off >>= 1) {
            s1 += __shfl_xor(s1, off);
            s2 += __shfl_xor(s2, off);
        }
        float mu  = s1 * (1.f / 256.f);
        float var = fmaxf(s2 * (1.f / 256.f) - mu * mu, 0.f);
        float inv = rsqrtf(var + 1e-5f);
        u16x4 o;
        o[0] = f2bf(fmaxf((x[0] - mu) * inv * lw.x + lb.x, 0.f));
        o[1] = f2bf(fmaxf((x[1] - mu) * inv * lw.y + lb.y, 0.f));
        o[2] = f2bf(fmaxf((x[2] - mu) * inv * lw.z + lb.z, 0.f));
        o[3] = f2bf(fmaxf((x[3] - mu) * inv * lw.w + lb.w, 0.f));
        *(u16x4*)&outp[(size_t)b * out_bs + i * 256 + c] = o;
    }
}

// weight transpose/cast + bias fuse + edge_mask. Wt3 padded to 128 rows.
__global__ __launch_bounds__(256)
void prep_k(const float* __restrict__ W1, const float* __restrict__ skip_w, const float* __restrict__ W2,
            const float* __restrict__ base_w1, const float* __restrict__ reg_w1, const float* __restrict__ res_w1,
            const float* __restrict__ skip_b, const float* __restrict__ base_b1, const float* __restrict__ reg_b1,
            const float* __restrict__ res_b1, const float* __restrict__ edge_logits,
            u16* __restrict__ Wt1, u16* __restrict__ Wt2, u16* __restrict__ Wt3,
            float* __restrict__ bias1, float* __restrict__ bias3,
            float* __restrict__ em2, float* __restrict__ em_out)
{
    int idx = blockIdx.x * 256 + threadIdx.x;
    if (idx < 512 * 256) {            // Wt1[n][k] = [W1|skip_w][k][n]
        int n = idx >> 8, k = idx & 255;
        float v = (n < 256) ? W1[k * 256 + n] : skip_w[k * 256 + (n - 256)];
        Wt1[n * 256 + k] = f2bf(v); return;
    }
    idx -= 512 * 256;
    if (idx < 256 * 256) {
        int n = idx >> 8, k = idx & 255;
        Wt2[n * 256 + k] = f2bf(W2[k * 256 + n]); return;
    }
    idx -= 256 * 256;
    if (idx < 128 * 1920) {           // Wt3 rows 80..127 zero
        int n = idx / 1920, k = idx % 1920;
        float v = (n < 32) ? base_w1[k * 32 + n]
                : (n < 64) ? reg_w1[k * 32 + (n - 32)]
                : (n < 80) ? res_w1[k * 16 + (n - 64)] : 0.f;
        Wt3[n * 1920 + k] = f2bf(v); return;
    }
    idx -= 128 * 1920;
    if (idx < 512) { bias1[idx] = (idx < 256) ? 0.f : skip_b[idx - 256]; return; }
    idx -= 512;
    if (idx < 80) {
        bias3[idx] = (idx < 32) ? base_b1[idx] : (idx < 64) ? reg_b1[idx - 32] : res_b1[idx - 64];
        return;
    }
    idx -= 80;
    if (idx < 49) {
        int i = idx / 7, j = idx % 7;
        float s = 1.f / (1.f + __expf(-edge_logits[idx]));
        float m = (i == j) ? 1.f : s;
        em2[idx * 2] = m;
        em2[idx * 2 + 1] = (1.f - m) * (-1e9f);
        em_out[idx] = m;
    }
}

__global__ __launch_bounds__(256)
void ctx_k(const float* __restrict__ ctx, u16* __restrict__ comb)
{
    int idx = blockIdx.x * 256 + threadIdx.x;   // B*128
    int b = idx >> 7, cc = idx & 127;
    comb[(size_t)b * 1920 + 1792 + cc] = f2bf(ctx[idx]);
}

// Heads; ho = 4 split-K partial slices (stride B*80), array-free accumulation.
__global__ __launch_bounds__(64)
void head_finish(const float* __restrict__ ho,
                 const float* __restrict__ bp, const float* __restrict__ rf,
                 const float* __restrict__ bw2, const float* __restrict__ bb2,
                 const float* __restrict__ rw2, const float* __restrict__ rb2,
                 const float* __restrict__ gw1, const float* __restrict__ gb1,
                 const float* __restrict__ gw2, const float* __restrict__ gb2,
                 const float* __restrict__ resw2, const float* __restrict__ resb2,
                 float* __restrict__ out_pred, float* __restrict__ out_w, float* __restrict__ out_gate, int B)
{
    int b = blockIdx.x * 64 + threadIdx.x;
    if (b >= B) return;
    const size_t ss = (size_t)B * 80;
    const float* p = ho + (size_t)b * 80;

    float z0 = bb2[0], z1 = bb2[1];
#pragma unroll
    for (int j = 0; j < 32; j += 4) {
        float4 a0 = *(const float4*)(p + j);
        float4 a1 = *(const float4*)(p + ss + j);
        float4 a2 = *(const float4*)(p + 2 * ss + j);
        float4 a3 = *(const float4*)(p + 3 * ss + j);
        float v;
        v = fmaxf((a0.x + a1.x) + (a2.x + a3.x), 0.f); z0 = fmaf(v, bw2[2*j+0], z0); z1 = fmaf(v, bw2[2*j+1], z1);
        v = fmaxf((a0.y + a1.y) + (a2.y + a3.y), 0.f); z0 = fmaf(v, bw2[2*j+2], z0); z1 = fmaf(v, bw2[2*j+3], z1);
        v = fmaxf((a0.z + a1.z) + (a2.z + a3.z), 0.f); z0 = fmaf(v, bw2[2*j+4], z0); z1 = fmaf(v, bw2[2*j+5], z1);
        v = fmaxf((a0.w + a1.w) + (a2.w + a3.w), 0.f); z0 = fmaf(v, bw2[2*j+6], z0); z1 = fmaf(v, bw2[2*j+7], z1);
    }
    float mz = fmaxf(z0, z1); float e0 = __expf(z0 - mz), e1 = __expf(z1 - mz); float inv = 1.f / (e0 + e1);
    float wb0 = e0 * inv, wb1 = e1 * inv;

    z0 = rb2[0]; z1 = rb2[1];
#pragma unroll
    for (int j = 0; j < 32; j += 4) {
        float4 a0 = *(const float4*)(p + 32 + j);
        float4 a1 = *(const float4*)(p + ss + 32 + j);
        float4 a2 = *(const float4*)(p + 2 * ss + 32 + j);
        float4 a3 = *(const float4*)(p + 3 * ss + 32 + j);
        float v;
        v = fmaxf((a0.x + a1.x) + (a2.x + a3.x), 0.f); z0 = fmaf(v, rw2[2*j+0], z0); z1 = fmaf(v, rw2[2*j+1], z1);
        v = fmaxf((a0.y + a1.y) + (a2.y + a3.y), 0.f); z0 = fmaf(v, rw2[2*j+2], z0); z1 = fmaf(v, rw2[2*j+3], z1);
        v = fmaxf((a0.z + a1.z) + (a2.z + a3.z), 0.f); z0 = fmaf(v, rw2[2*j+4], z0); z1 = fmaf(v, rw2[2*j+5], z1);
        v = fmaxf((a0.w + a1.w) + (a2.w + a3.w), 0.f); z0 = fmaf(v, rw2[2*j+6], z0); z1 = fmaf(v, rw2[2*j+7], z1);
    }
    mz = fmaxf(z0, z1); e0 = __expf(z0 - mz); e1 = __expf(z1 - mz); inv = 1.f / (e0 + e1);
    float wr0 = e0 * inv, wr1 = e1 * inv;

    float r = resb2[0];
#pragma unroll
    for (int j = 0; j < 16; j += 4) {
        float4 a0 = *(const float4*)(p + 64 + j);
        float4 a1 = *(const float4*)(p + ss + 64 + j);
        float4 a2 = *(const float4*)(p + 2 * ss + 64 + j);
        float4 a3 = *(const float4*)(p + 3 * ss + 64 + j);
        r = fmaf(fast_tanh((a0.x + a1.x) + (a2.x + a3.x)), resw2[j + 0], r);
        r = fmaf(fast_tanh((a0.y + a1.y) + (a2.y + a3.y)), resw2[j + 1], r);
        r = fmaf(fast_tanh((a0.z + a1.z) + (a2.z + a3.z)), resw2[j + 2], r);
        r = fmaf(fast_tanh((a0.w + a1.w) + (a2.w + a3.w)), resw2[j + 3], r);
    }

    float g = gb2[0];
#pragma unroll
    for (int j = 0; j < 8; ++j) {
        float a = gb1[j];
#pragma unroll
        for (int i = 0; i < 3; ++i) a += rf[(size_t)b * 3 + i] * gw1[i * 8 + j];
        g += fast_tanh(a) * gw2[j];
    }
    float gg = 1.f / (1.f + __expf(-g));
    float w0 = (1.f - gg) * wb0 + gg * wr0;
    float w1 = (1.f - gg) * wb1 + gg * wr1;
    float pred = w0 * bp[(size_t)b * 2] + w1 * bp[(size_t)b * 2 + 1];
    pred = fmaxf(pred + r * 0.05f, 0.05f);
    out_pred[b] = pred;
    out_w[(size_t)b * 2] = w0; out_w[(size_t)b * 2 + 1] = w1;
    out_gate[b] = gg;
}

extern "C" void kernel_launch(void* const* d_in, const int* in_sizes, int n_in,
                              void* d_out, int out_size, void* d_ws, size_t ws_size,
                              hipStream_t stream)
{
    const int B = in_sizes[1] / 128;     // context is (B,128)
    const int Mbig = B * 7;

    const float* node_feats   = (const float*)d_in[0];
    const float* context      = (const float*)d_in[1];
    const float* base_preds   = (const float*)d_in[2];
    const float* regime_feats = (const float*)d_in[3];
    const float* edge_logits  = (const float*)d_in[4];
    const float* W1      = (const float*)d_in[5];
    const float* a_src1  = (const float*)d_in[6];
    const float* a_dst1  = (const float*)d_in[7];
    const float* W2      = (const float*)d_in[8];
    const float* a_src2  = (const float*)d_in[9];
    const float* a_dst2  = (const float*)d_in[10];
    const float* ln1_w   = (const float*)d_in[11];
    const float* ln1_b   = (const float*)d_in[12];
    const float* ln2_w   = (const float*)d_in[13];
    const float* ln2_b   = (const float*)d_in[14];
    const float* skip_w  = (const float*)d_in[15];
    const float* skip_b  = (const float*)d_in[16];
    const float* base_w1 = (const float*)d_in[17];
    const float* base_b1 = (const float*)d_in[18];
    const float* base_w2 = (const float*)d_in[19];
    const float* base_b2 = (const float*)d_in[20];
    const float* reg_w1  = (const float*)d_in[21];
    const float* reg_b1  = (const float*)d_in[22];
    const float* reg_w2  = (const float*)d_in[23];
    const float* reg_b2  = (const float*)d_in[24];
    const float* gate_w1 = (const float*)d_in[25];
    const float* gate_b1 = (const float*)d_in[26];
    const float* gate_w2 = (const float*)d_in[27];
    const float* gate_b2 = (const float*)d_in[28];
    const float* res_w1  = (const float*)d_in[29];
    const float* res_b1  = (const float*)d_in[30];
    const float* res_w2  = (const float*)d_in[31];
    const float* res_b2  = (const float*)d_in[32];

    // workspace layout (bytes)
    char* ws = (char*)d_ws;
    size_t off = 0;
    u16* hs1 = (u16*)(ws + off);                       // [h1_pre|skip] Mbig x 512 bf16
    u16* hh2 = (u16*)(ws + off);                       // reuse after GAT1: Mbig x 256 bf16
    off += (size_t)Mbig * 512 * 2;
    u16* hbuf = (u16*)(ws + off);  off += (size_t)Mbig * 256 * 2;   // h: Mbig x 256 bf16
    u16* comb = (u16*)(ws + off);  off += (size_t)B * 1920 * 2;     // combined: B x 1920 bf16
    u16* nf_bf = comb;             // A1 bf16 aliases comb (dead until step 9)
    float* headout = (float*)(ws + off); off += (size_t)4 * B * 80 * 4; // 4 split-K slices
    u16* Wt1 = (u16*)(ws + off); off += 512 * 256 * 2;
    u16* Wt2 = (u16*)(ws + off); off += 256 * 256 * 2;
    u16* Wt3 = (u16*)(ws + off); off += (size_t)128 * 1920 * 2;     // padded to 128 rows
    float* bias1 = (float*)(ws + off); off += 512 * 4;
    float* bias3 = (float*)(ws + off); off += 128 * 4;
    float* em2   = (float*)(ws + off); off += 128 * 4;
    float* scoresb = (float*)(ws + off); off += (size_t)Mbig * 8 * 4;   // row scores f32
    float* alphab  = (float*)(ws + off); off += (size_t)B * 4 * 49 * 4; // alpha f32

    float* out_pred = (float*)d_out;
    float* out_w    = out_pred + B;
    float* out_gate = out_pred + 3 * (size_t)B;
    float* out_em   = out_pred + 4 * (size_t)B;
    float* out_attn = out_pred + 4 * (size_t)B + 49;

    const int B4blocks = (B * 4) / 256;

    // 0. node_feats f32 -> bf16 (HBM-bound streaming pass)
    {
        int n8 = Mbig * 256 / 8;
        precast_k<<<dim3((n8 + 255) / 256), dim3(256), 0, stream>>>(node_feats, nf_bf, n8);
    }

    // 1. weight prep + edge mask
    prep_k<<<dim3(1731), dim3(256), 0, stream>>>(W1, skip_w, W2, base_w1, reg_w1, res_w1,
        skip_b, base_b1, reg_b1, res_b1, edge_logits, Wt1, Wt2, Wt3, bias1, bias3, em2, out_em);

    // 2. GEMM1: nf_bf @ [W1|skip_w] -> hs1 (bf16), bias=[0|skip_b]
    gemm_k<1, 0, 0><<<dim3((Mbig / 128) * 4, 1), dim3(256), 0, stream>>>(
        nf_bf, Wt1, bias1, (void*)hs1, Mbig, 512, 256, 256, 512, 4, 256);

    // 3. scores from h1 (= hs1 cols 0..255)
    score_k<<<dim3(Mbig / 4), dim3(256), 0, stream>>>(hs1, 512, a_src1, a_dst1, scoresb, Mbig);

    // 4. alpha for GAT1
    alpha_k<0><<<dim3(B4blocks), dim3(256), 0, stream>>>(scoresb, em2, alphab, (float*)nullptr);

    // 5. GAT1 apply: PV + skip-resid + LN1 + relu -> hbuf
    gat_apply_k<<<dim3(B / 4), dim3(256), 0, stream>>>(
        hs1, 512, hs1, 512, 256, alphab, ln1_w, ln1_b, hbuf, 1792);

    // 6. GEMM2: h @ W2 -> hh2 (reuses hs1 region)
    gemm_k<0, 0, 0><<<dim3((Mbig / 128) * 2, 1), dim3(256), 0, stream>>>(
        hbuf, Wt2, (const float*)nullptr, (void*)hh2, Mbig, 256, 256, 256, 256, 2, 256);

    // 7. scores from h2
    score_k<<<dim3(Mbig / 4), dim3(256), 0, stream>>>(hh2, 256, a_src2, a_dst2, scoresb, Mbig);

    // 8. alpha for GAT2 (+ attn mean output)
    alpha_k<1><<<dim3(B4blocks), dim3(256), 0, stream>>>(scoresb, em2, alphab, out_attn);

    // 9. GAT2 apply: PV + h-resid + LN2 + relu -> comb[:, :1792]
    gat_apply_k<<<dim3(B / 4), dim3(256), 0, stream>>>(
        hh2, 256, hbuf, 256, 0, alphab, ln2_w, ln2_b, comb, 1920);

    // 10. context -> comb[:, 1792:]
    ctx_k<<<dim3(B * 128 / 256), dim3(256), 0, stream>>>(context, comb);

    // 11. GEMM3: comb @ padded-Wt3 + bias -> 4 partial slices (split-K x4, no memset)
    gemm_k<1, 1, 1><<<dim3(B / 128, 4), dim3(256), 0, stream>>>(
        comb, Wt3, bias3, (void*)headout, B, 80, 1920, 1920, 80, 1, 480);

    // 12. heads -> pred, weights, gate (sums the 4 partials, array-free)
    head_finish<<<dim3((B + 63) / 64), dim3(64), 0, stream>>>(
        headout, base_preds, regime_feats, base_w2, base_b2, reg_w2, reg_b2,
        gate_w1, gate_b1, gate_w2, gate_b2, res_w2, res_b2, out_pred, out_w, out_gate, B);
}